// Round 5
// baseline (194.457 us; speedup 1.0000x reference)
//
#include <hip/hip_runtime.h>
#include <hip/hip_bf16.h>

#define B_  8
#define H_  512
#define L_  2048
#define D2_ 32
#define NC_ 64
#define LC_ 32    // L_/NC_
#define EP  36    // E_lds row pitch in u32 (16B-aligned rows)

typedef __attribute__((ext_vector_type(8))) short short8;     // 8 bf16 (4 VGPRs)
typedef __attribute__((ext_vector_type(8))) _Float16 half8;   // 8 fp16 (4 VGPRs)
typedef __attribute__((ext_vector_type(2))) _Float16 half2v;  // packed fp16 (v_pk_*)
typedef __attribute__((ext_vector_type(4))) float float4v;    // 4 fp32 acc

__device__ __forceinline__ half2v pk_fma16(half2v a, half2v b, half2v c) {
    return __builtin_elementwise_fma(a, b, c);
}

// tanh-form GELU: max |err| vs exact ~3e-4, far below bf16 y-storage ulp.
__device__ __forceinline__ float gelu_fast(float x) {
    float q = x * fmaf(0.044715f, x * x, 1.0f);
    float s = __expf(-1.5957691216057308f * q);   // e^{-2*0.79788456*q}
    return __fdividef(x, 1.0f + s);               // x * sigmoid(2w)
}

__device__ __forceinline__ unsigned pack_bf16x2(float x, float y) {
    __hip_bfloat162 p = __float22bfloat162_rn(make_float2(x, y));
    return *(unsigned*)&p;
}
__device__ __forceinline__ float2 unpack_bf16x2(unsigned v) {
    __hip_bfloat162 p = *(__hip_bfloat162*)&v;
    return __bfloat1622float2(p);
}
__device__ __forceinline__ unsigned pack_f16x2(float x, float y) {
    auto v = __builtin_amdgcn_cvt_pkrtz(x, y);    // v_cvt_pkrtz_f16_f32
    return *(unsigned*)&v;
}

__device__ __forceinline__ void load_lds16(const void* g, void* l) {
    __builtin_amdgcn_global_load_lds((const __attribute__((address_space(1))) unsigned int*)g,
                                     (__attribute__((address_space(3))) unsigned int*)l, 16, 0, 0);
}

// ---------------- cast W -> bf16, fused param prep ----------------
// WPh (fp16): per-h chunk-combine multipliers P^(2^k), P = w^32, k=0..5.
// u32 view: [(h*6+k)*32 + j] = {Mr_2j, Mr_2j+1}; [+16+j] = {Mi_2j, Mi_2j+1}.
__global__ void cast_prep_kernel(const float* __restrict__ W, __hip_bfloat16* __restrict__ Wb,
                                 const float* __restrict__ a, const float* __restrict__ th,
                                 const float* __restrict__ bb, const float* __restrict__ cc,
                                 const float* __restrict__ x0,
                                 float* __restrict__ aT, float* __restrict__ thT,
                                 float* __restrict__ qT, float* __restrict__ gxT,
                                 _Float16* __restrict__ WPh) {
    int tid = blockIdx.x * 256 + threadIdx.x;   // 262144
    Wb[tid] = __float2bfloat16(W[tid]);
    if (tid < H_ * D2_) {                        // tid = d*H + h (d-major)
        int h = tid & (H_ - 1);
        int d = tid >> 9;
        const float T = 1.0f / (float)(L_ - 1);
        float av = -fabsf(a[h * D2_ + d]);
        float tv = th[h * D2_ + d];
        float q  = bb[h * D2_ + d] * cc[h * D2_ + d];
        aT[tid]  = av;
        thT[tid] = tv;
        qT[tid]  = q;
        gxT[tid] = 2.0f * cc[h * D2_ + d] * x0[h * D2_ + d];
        #pragma unroll
        for (int k = 0; k < 6; ++k) {
            float len = (float)(32 << k);        // 32 * 2^k steps
            float e2  = __expf(av * T * len);
            float an  = tv * T * len;
            WPh[((size_t)h * 6 + k) * 64 + d]      = (_Float16)(e2 * __cosf(an));
            WPh[((size_t)h * 6 + k) * 64 + 32 + d] = (_Float16)(e2 * __sinf(an));
        }
    }
}

// ---------------- fkprep: fk (SSM kernel f, k0) + MFMA operand build, one block per h ----
__global__ __launch_bounds__(256) void fkprep_kernel(
        const float* __restrict__ aT, const float* __restrict__ thT,
        const float* __restrict__ qT, const float* __restrict__ gxT,
        unsigned* __restrict__ FKf, _Float16* __restrict__ AB,
        _Float16* __restrict__ CB) {
    __shared__ float f_lds[32];
    int h = blockIdx.x;
    int t = threadIdx.x;
    int q4 = t & 3, lc = t >> 2;
    const float T = 1.0f / (float)(L_ - 1);
    float z0 = T * (float)(lc * 32);
    float pr[8], pi[8], wr[8], wi[8], qd[8], gx[8];
    #pragma unroll
    for (int j = 0; j < 8; ++j) {
        int idx = (q4 * 8 + j) * H_ + h;
        float aa = aT[idx], tv = thT[idx];
        float e0 = __expf(aa * z0);
        pr[j] = e0 * __cosf(tv * z0);
        pi[j] = e0 * __sinf(tv * z0);
        float e1 = __expf(aa * T);
        wr[j] = e1 * __cosf(tv * T);
        wi[j] = e1 * __sinf(tv * T);
        qd[j] = qT[idx];
        gx[j] = gxT[idx];
    }
    for (int i = 0; i < 32; ++i) {
        float fa = 0.f, ka = 0.f;
        #pragma unroll
        for (int j = 0; j < 8; ++j) {
            fa = fmaf(qd[j], pr[j], fa);
            ka = fmaf(gx[j], pr[j], ka);
            float nr = fmaf(pr[j], wr[j], -(pi[j] * wi[j]));
            float ni = fmaf(pr[j], wi[j],  (pi[j] * wr[j]));
            pr[j] = nr; pi[j] = ni;
        }
        fa += __shfl_xor(fa, 1); fa += __shfl_xor(fa, 2);
        ka += __shfl_xor(ka, 1); ka += __shfl_xor(ka, 2);
        if (q4 == 0) {
            float fv = 2.0f * T * fa;
            FKf[(size_t)h * L_ + lc * 32 + i] = pack_bf16x2(fv, ka);
            if (lc == 0) f_lds[i] = fv;
        }
    }
    __syncthreads();
    // ---- phase 2: operand matrices (fp16) ----
    for (int e = t; e < 64 * 32; e += 256) {
        int m = e >> 5, i = e & 31;
        int d = m & 31;
        float av = aT[d * H_ + h], tv = thT[d * H_ + h];
        float z  = T * (float)(31 - i);
        float ex = __expf(av * z);
        float v  = (m < 32) ? ex * __cosf(tv * z) : ex * __sinf(tv * z);
        AB[(size_t)h * 2048 + e] = (_Float16)v;
    }
    for (int e = t; e < 32 * 96; e += 256) {
        int i = e / 96, k = e - i * 96;
        float v = 0.f;
        if (k < 32) {
            if (k <= i) v = f_lds[i - k];
        } else {
            int d = (k < 64) ? k - 32 : k - 64;
            float av = aT[d * H_ + h], tv = thT[d * H_ + h];
            float qs = 2.0f * T * qT[d * H_ + h];
            float z  = T * (float)(i + 1);
            float ex = __expf(av * z);
            v = (k < 64) ? qs * ex * __cosf(tv * z) : -qs * ex * __sinf(tv * z);
        }
        CB[(size_t)h * 3072 + e] = (_Float16)v;
    }
}

// ---------------- scan_mfma v3: 2 waves x 2 batch rows per block ----------------
// Grid (H, B/2). Each block: h = bx, b in {2*by, 2*by+1}. Wave wid owns d-half
// [wid*16, wid*16+16) for BOTH b's. Two independent (b) instruction streams give
// ~2x ILP in every latency-bound phase (HBM loads, shfl-scan chain, MFMA deps);
// h-params (AB/CB/WPh/FKf) are loaded once and shared across both b's.
__global__ __launch_bounds__(128, 4) void scan_mfma_kernel(
        const float* __restrict__ u, const _Float16* __restrict__ AB,
        const _Float16* __restrict__ CB, const unsigned* __restrict__ WPh,
        const float* __restrict__ Dp, const unsigned* __restrict__ FKf,
        __hip_bfloat16* __restrict__ y) {
    __shared__ __align__(16) unsigned El[2][64 * EP];
    int wid = threadIdx.x >> 6, lane = threadIdx.x & 63;
    int h = blockIdx.x, b0 = blockIdx.y * 2;
    int ln = lane & 15, qq = lane >> 4;
    const float* ug[2] = { u + (size_t)(b0 * H_ + h) * L_,
                           u + (size_t)((b0 + 1) * H_ + h) * L_ };

    // ---- U fragments (fp16), both b's, all 4 column-tiles ----
    half8 uf[2][4];
    float u0[2];
    #pragma unroll
    for (int bi = 0; bi < 2; ++bi) {
        u0[bi] = ug[bi][0];
        #pragma unroll
        for (int nb = 0; nb < 4; ++nb) {
            const float* p = ug[bi] + (nb * 16 + ln) * 32 + qq * 8;
            float4 a0 = *(const float4*)p;
            float4 a1 = *(const float4*)(p + 4);
            unsigned* vp = (unsigned*)&uf[bi][nb];
            vp[0] = pack_f16x2(a0.x, a0.y);
            vp[1] = pack_f16x2(a0.z, a0.w);
            vp[2] = pack_f16x2(a1.x, a1.y);
            vp[3] = pack_f16x2(a1.z, a1.w);
        }
    }

    // ---- M1: this wave's Er/Ei rows (d-half), both b's ----
    const _Float16* ABh = AB + (size_t)h * 2048;
    int j0 = wid * 8 + qq * 2;
    #pragma unroll
    for (int e = 0; e < 2; ++e) {       // e=0: Re rows, e=1: Im rows
        half8 af = *(const half8*)&ABh[(e * 32 + wid * 16 + ln) * 32 + qq * 8];
        #pragma unroll
        for (int bi = 0; bi < 2; ++bi)
            #pragma unroll
            for (int nb = 0; nb < 4; ++nb) {
                float4v acc = (float4v){0.f, 0.f, 0.f, 0.f};
                acc = __builtin_amdgcn_mfma_f32_16x16x32_f16(af, uf[bi][nb], acc, 0, 0, 0);
                *(uint2*)&El[bi][(nb * 16 + ln) * EP + e * 16 + j0] =
                    make_uint2(pack_f16x2(acc[0], acc[1]), pack_f16x2(acc[2], acc[3]));
            }
    }
    // own-wave write->read: DS ops drain, no cross-wave dependency yet
    asm volatile("s_waitcnt lgkmcnt(0)" ::: "memory");
    __builtin_amdgcn_sched_barrier(0);

    // ---- packed-fp16 scan over chunks (lane = c), own 8 pairs, both b's ----
    int c = lane;
    unsigned sr[2][8], si[2][8];
    #pragma unroll
    for (int bi = 0; bi < 2; ++bi) {
        const unsigned* rp = &El[bi][c * EP + wid * 8];
        uint4 r0 = *(const uint4*)rp;
        uint4 r1 = *(const uint4*)(rp + 4);
        uint4 i0 = *(const uint4*)(rp + 16);
        uint4 i1 = *(const uint4*)(rp + 20);
        sr[bi][0]=r0.x; sr[bi][1]=r0.y; sr[bi][2]=r0.z; sr[bi][3]=r0.w;
        sr[bi][4]=r1.x; sr[bi][5]=r1.y; sr[bi][6]=r1.z; sr[bi][7]=r1.w;
        si[bi][0]=i0.x; si[bi][1]=i0.y; si[bi][2]=i0.z; si[bi][3]=i0.w;
        si[bi][4]=i1.x; si[bi][5]=i1.y; si[bi][6]=i1.z; si[bi][7]=i1.w;
    }
    const unsigned* mpb = WPh + (size_t)h * 6 * 32;
    #pragma unroll
    for (int st = 0; st < 6; ++st) {
        int off = 1 << st;
        int src = (c - off) & 63;
        bool act = c >= off;
        const unsigned* mp = mpb + st * 32 + wid * 8;
        #pragma unroll
        for (int jj = 0; jj < 8; ++jj) {
            unsigned mru = mp[jj];
            unsigned miu = mp[16 + jj];
            unsigned min_ = miu ^ 0x80008000u;          // -Mi via sign flip
            #pragma unroll
            for (int bi = 0; bi < 2; ++bi) {
                unsigned prp = (unsigned)__shfl((int)sr[bi][jj], src);
                unsigned pip = (unsigned)__shfl((int)si[bi][jj], src);
                if (!act) { prp = 0u; pip = 0u; }
                half2v pr = *(half2v*)&prp, pi = *(half2v*)&pip;
                half2v Mr = *(half2v*)&mru, Mi = *(half2v*)&miu, Mni = *(half2v*)&min_;
                half2v s_r = *(half2v*)&sr[bi][jj], s_i = *(half2v*)&si[bi][jj];
                half2v nr = pk_fma16(pr, Mr, pk_fma16(pi, Mni, s_r));
                half2v ni = pk_fma16(pr, Mi, pk_fma16(pi, Mr,  s_i));
                sr[bi][jj] = *(unsigned*)&nr; si[bi][jj] = *(unsigned*)&ni;
            }
        }
    }
    {   // exclusive shift: carry entering chunk c = S_{c-1}; lane 0 -> 0
        int srcm1 = (c - 1) & 63;
        #pragma unroll
        for (int bi = 0; bi < 2; ++bi)
            #pragma unroll
            for (int jj = 0; jj < 8; ++jj) {
                unsigned a0 = (unsigned)__shfl((int)sr[bi][jj], srcm1);
                unsigned b1 = (unsigned)__shfl((int)si[bi][jj], srcm1);
                if (c == 0) { a0 = 0u; b1 = 0u; }
                sr[bi][jj] = a0; si[bi][jj] = b1;
            }
    }
    #pragma unroll
    for (int bi = 0; bi < 2; ++bi) {    // carries back to same El slots
        unsigned* wp = &El[bi][c * EP + wid * 8];
        *(uint4*)wp        = make_uint4(sr[bi][0], sr[bi][1], sr[bi][2], sr[bi][3]);
        *(uint4*)(wp + 4)  = make_uint4(sr[bi][4], sr[bi][5], sr[bi][6], sr[bi][7]);
        *(uint4*)(wp + 16) = make_uint4(si[bi][0], si[bi][1], si[bi][2], si[bi][3]);
        *(uint4*)(wp + 20) = make_uint4(si[bi][4], si[bi][5], si[bi][6], si[bi][7]);
    }
    // prefetch FK for epilogue (h-only, shared by both b's)
    const unsigned* fgh = FKf + (size_t)h * L_;
    uint4 fkp[2][2];
    #pragma unroll
    for (int nbi = 0; nbi < 2; ++nbi) {
        int col = (2 * wid + nbi) * 16 + ln;
        fkp[nbi][0] = *(const uint4*)&fgh[col * 32 + qq * 4];
        fkp[nbi][1] = *(const uint4*)&fgh[col * 32 + 16 + qq * 4];
    }
    __syncthreads();

    // ---- M2 + epilogue, per b (serial; two rounds pipeline back-to-back) ----
    const _Float16* CBh = CB + (size_t)h * 3072;
    float f0; { f0 = unpack_bf16x2(fgh[0]).x; }
    float c0v = Dp[h] - 0.5f * f0;
    #pragma unroll
    for (int bi = 0; bi < 2; ++bi) {
        float c1v = -0.5f * u0[bi];
        float4v acc2[2][2];
        #pragma unroll
        for (int mb = 0; mb < 2; ++mb)
            #pragma unroll
            for (int nbi = 0; nbi < 2; ++nbi)
                acc2[mb][nbi] = (float4v){0.f, 0.f, 0.f, 0.f};
        #pragma unroll
        for (int ks = 0; ks < 3; ++ks) {
            half8 a2[2];
            a2[0] = *(const half8*)&CBh[(ln)      * 96 + ks * 32 + qq * 8];
            a2[1] = *(const half8*)&CBh[(16 + ln) * 96 + ks * 32 + qq * 8];
            #pragma unroll
            for (int nbi = 0; nbi < 2; ++nbi) {
                int col = (2 * wid + nbi) * 16 + ln;
                half8 bfv;
                if (ks == 0) bfv = uf[bi][2 * wid + nbi];
                else {
                    int off = (ks == 1) ? 0 : 16;
                    bfv = *(const half8*)&El[bi][col * EP + off + qq * 4];
                }
                acc2[0][nbi] = __builtin_amdgcn_mfma_f32_16x16x32_f16(a2[0], bfv, acc2[0][nbi], 0, 0, 0);
                acc2[1][nbi] = __builtin_amdgcn_mfma_f32_16x16x32_f16(a2[1], bfv, acc2[1][nbi], 0, 0, 0);
            }
        }
        #pragma unroll
        for (int nbi = 0; nbi < 2; ++nbi) {
            int col = (2 * wid + nbi) * 16 + ln;
            #pragma unroll
            for (int mb = 0; mb < 2; ++mb) {
                int l0 = col * 32 + mb * 16 + qq * 4;
                float4 u4 = *(const float4*)(ug[bi] + l0);
                uint4 fkv = fkp[nbi][mb];
                float us[4] = {u4.x, u4.y, u4.z, u4.w};
                unsigned fs[4] = {fkv.x, fkv.y, fkv.z, fkv.w};
                float g[4];
                #pragma unroll
                for (int r = 0; r < 4; ++r) {
                    float2 fk = unpack_bf16x2(fs[r]);
                    float yv = acc2[mb][nbi][r] + fmaf(c0v, us[r], fmaf(c1v, fk.x, fk.y));
                    g[r] = gelu_fast(yv);
                }
                uint2 yo;
                yo.x = pack_bf16x2(g[0], g[1]);
                yo.y = pack_bf16x2(g[2], g[3]);
                *(uint2*)((short*)y + (size_t)((b0 + bi) * H_ + h) * L_ + l0) = yo;
            }
        }
    }
}

// ---------------- transpose y[b][f][l] -> yT[b][l][f] (bf16) ----------------
// XOR-swizzle the l-index with 8*(f>>3): removes the 8-way LDS read conflict
// (576*(t&7) ≡ 0 mod 64 made all col-groups alias one bank). Keeps uint4
// write contiguity (XOR in units of 8 elements) and 16B alignment.
__global__ __launch_bounds__(256) void transpose_y_kernel(
        const __hip_bfloat16* __restrict__ y, __hip_bfloat16* __restrict__ yT) {
    __shared__ short tile[64][72];
    int l0 = blockIdx.x * 64, f0 = blockIdx.y * 64, b = blockIdx.z;
    int t = threadIdx.x;
    int row = t >> 3, col8 = (t & 7) * 8;
    const short* yg = (const short*)y + (size_t)b * H_ * L_;
    #pragma unroll
    for (int r2 = 0; r2 < 64; r2 += 32) {
        int fr = row + r2;
        *(uint4*)&tile[fr][col8 ^ (8 * ((fr >> 3) & 7))] =
            *(const uint4*)&yg[(size_t)(f0 + fr) * L_ + l0 + col8];
    }
    __syncthreads();
    short* og = (short*)yT + (size_t)b * L_ * H_;
    #pragma unroll
    for (int r2 = 0; r2 < 64; r2 += 32) {
        int lrow = row + r2;
        short v[8];
        #pragma unroll
        for (int j = 0; j < 8; ++j) {
            int f = col8 + j;
            v[j] = tile[f][lrow ^ (8 * ((f >> 3) & 7))];
        }
        *(uint4*)&og[(size_t)(l0 + lrow) * H_ + f0 + col8] = *(uint4*)v;
    }
}

// ---------------- gemm: out[b,h,l] = sum_f W[h,f] * yT[b,l,f] + bias[h] ----------------
// 64x128 tile, grid 1024 blocks (4/CU, 16 waves/CU).
__global__ __launch_bounds__(256) void gemm_kernel(
        const __hip_bfloat16* __restrict__ Wb, const __hip_bfloat16* __restrict__ yT,
        const float* __restrict__ bias, float* __restrict__ out) {
    __shared__ __align__(16) short As[64 * 32];
    __shared__ __align__(16) short Bs[128 * 32];
    int l0 = blockIdx.x * 128;
    int h0 = blockIdx.y * 64;
    int b  = blockIdx.z;
    int t    = threadIdx.x;
    int lane = t & 63, wave = t >> 6;
    int m_off = (wave >> 1) * 32, n_off = (wave & 1) * 64;
    int quad = lane >> 4, ln = lane & 15;

    float4v acc[2][4];
    #pragma unroll
    for (int mt = 0; mt < 2; ++mt)
        #pragma unroll
        for (int nt = 0; nt < 4; ++nt)
            acc[mt][nt] = (float4v){0.f, 0.f, 0.f, 0.f};

    const short* Wg = (const short*)Wb;
    const short* Yg = (const short*)(yT + (size_t)b * L_ * H_);

    int r  = t >> 2;       // 0..63
    int qd = t & 3;

    for (int kt = 0; kt < 16; ++kt) {
        int k0 = kt * 32;
        load_lds16(Wg + (h0 + r) * 512 + k0 + qd * 8, &As[t * 8]);
        load_lds16(Yg + (size_t)(l0 + r)      * 512 + k0 + qd * 8, &Bs[t * 8]);
        load_lds16(Yg + (size_t)(l0 + r + 64) * 512 + k0 + qd * 8, &Bs[(t + 256) * 8]);
        __syncthreads();

        short8 af[2], bf[4];
        #pragma unroll
        for (int mt = 0; mt < 2; ++mt)
            af[mt] = *(const short8*)&As[(m_off + mt * 16 + ln) * 32 + quad * 8];
        #pragma unroll
        for (int nt = 0; nt < 4; ++nt)
            bf[nt] = *(const short8*)&Bs[(n_off + nt * 16 + ln) * 32 + quad * 8];
        #pragma unroll
        for (int mt = 0; mt < 2; ++mt)
            #pragma unroll
            for (int nt = 0; nt < 4; ++nt)
                acc[mt][nt] = __builtin_amdgcn_mfma_f32_16x16x32_bf16(
                    af[mt], bf[nt], acc[mt][nt], 0, 0, 0);
        __syncthreads();
    }

    #pragma unroll
    for (int mt = 0; mt < 2; ++mt) {
        #pragma unroll
        for (int nt = 0; nt < 4; ++nt) {
            int hh = h0 + m_off + mt * 16 + quad * 4;
            int ll = l0 + n_off + nt * 16 + ln;
            #pragma unroll
            for (int r2 = 0; r2 < 4; ++r2)
                out[((size_t)(b * H_ + hh + r2)) * L_ + ll] = acc[mt][nt][r2] + bias[hh + r2];
        }
    }
}

extern "C" void kernel_launch(void* const* d_in, const int* in_sizes, int n_in,
                              void* d_out, int out_size, void* d_ws, size_t ws_size,
                              hipStream_t stream) {
    const float* u    = (const float*)d_in[0];
    const float* a    = (const float*)d_in[1];
    const float* th   = (const float*)d_in[2];
    const float* bb   = (const float*)d_in[3];
    const float* cc   = (const float*)d_in[4];
    const float* x0   = (const float*)d_in[5];
    const float* Dp   = (const float*)d_in[6];
    const float* W    = (const float*)d_in[7];
    const float* bias = (const float*)d_in[8];
    float* out = (float*)d_out;
    char* ws = (char*)d_ws;

    // layout: FKf 4M @0 | yT 16M @4M | y 16M @20M | Wb 0.5M @36M | AB 2M @37M |
    //         CB 3M @39M | params @42M: aT,thT,qT,gxT (4x64KB) + WPh fp16 (384KB)
    unsigned*       FKf = (unsigned*)ws;
    __hip_bfloat16* yT  = (__hip_bfloat16*)(ws + (4ull  << 20));
    __hip_bfloat16* y   = (__hip_bfloat16*)(ws + (20ull << 20));
    __hip_bfloat16* Wb  = (__hip_bfloat16*)(ws + (36ull << 20));
    _Float16*       AB  = (_Float16*)(ws + (37ull << 20));
    _Float16*       CB  = (_Float16*)(ws + (39ull << 20));
    float* pbase = (float*)(ws + (42ull << 20));
    float *aT  = pbase,           *thT = pbase + 16384, *qT = pbase + 2*16384,
          *gxT = pbase + 3*16384;
    _Float16* WPh = (_Float16*)(pbase + 4*16384);

    hipLaunchKernelGGL(cast_prep_kernel,  dim3(1024),      dim3(256), 0, stream,
                       W, Wb, a, th, bb, cc, x0, aT, thT, qT, gxT, WPh);
    hipLaunchKernelGGL(fkprep_kernel,     dim3(H_),        dim3(256), 0, stream,
                       aT, thT, qT, gxT, FKf, AB, CB);
    hipLaunchKernelGGL(scan_mfma_kernel,  dim3(H_, B_/2),  dim3(128), 0, stream,
                       u, AB, CB, (const unsigned*)WPh, Dp, FKf, y);
    hipLaunchKernelGGL(transpose_y_kernel,dim3(32, 8, 8),  dim3(256), 0, stream, y, yT);
    hipLaunchKernelGGL(gemm_kernel,       dim3(16, 8, 8),  dim3(256), 0, stream,
                       Wb, yT, bias, out);
}

// Round 6
// 169.365 us; speedup vs baseline: 1.1482x; 1.1482x over previous
//
#include <hip/hip_runtime.h>
#include <hip/hip_bf16.h>

#define B_  8
#define H_  512
#define L_  2048
#define D2_ 32
#define NC_ 64
#define LC_ 32    // L_/NC_
#define EP  36    // E_lds row pitch in u32 (16B-aligned rows)

typedef __attribute__((ext_vector_type(8))) short short8;     // 8 bf16 (4 VGPRs)
typedef __attribute__((ext_vector_type(8))) _Float16 half8;   // 8 fp16 (4 VGPRs)
typedef __attribute__((ext_vector_type(2))) _Float16 half2v;  // packed fp16 (v_pk_*)
typedef __attribute__((ext_vector_type(4))) float float4v;    // 4 fp32 acc

__device__ __forceinline__ half2v pk_fma16(half2v a, half2v b, half2v c) {
    return __builtin_elementwise_fma(a, b, c);
}

// tanh-form GELU: max |err| vs exact ~3e-4, far below bf16 y-storage ulp.
__device__ __forceinline__ float gelu_fast(float x) {
    float q = x * fmaf(0.044715f, x * x, 1.0f);
    float s = __expf(-1.5957691216057308f * q);   // e^{-2*0.79788456*q}
    return __fdividef(x, 1.0f + s);               // x * sigmoid(2w)
}

__device__ __forceinline__ unsigned pack_bf16x2(float x, float y) {
    __hip_bfloat162 p = __float22bfloat162_rn(make_float2(x, y));
    return *(unsigned*)&p;
}
__device__ __forceinline__ float2 unpack_bf16x2(unsigned v) {
    __hip_bfloat162 p = *(__hip_bfloat162*)&v;
    return __bfloat1622float2(p);
}
__device__ __forceinline__ unsigned pack_f16x2(float x, float y) {
    auto v = __builtin_amdgcn_cvt_pkrtz(x, y);    // v_cvt_pkrtz_f16_f32
    return *(unsigned*)&v;
}

__device__ __forceinline__ void load_lds16(const void* g, void* l) {
    __builtin_amdgcn_global_load_lds((const __attribute__((address_space(1))) unsigned int*)g,
                                     (__attribute__((address_space(3))) unsigned int*)l, 16, 0, 0);
}

// ---------------- fkprep: params + fk (f,k0) + MFMA operands + W-cast, 1 block/h ----
// Absorbs the old cast_prep: per-h params computed from raw inputs into LDS,
// WPh (P^(2^k) multipliers) written here, W row cast here. One fewer launch,
// no aT/thT/qT/gxT global round-trip.
// Phase 1 (fk): thread (q4 = t&3, lc = t>>2): d in [q4*8, q4*8+8), l in [lc*32,+32).
//   FKf[h*L + l] = bf16x2{ f[h,l], k0[h,l] }; f[0..31] kept in LDS (fp32).
// Phase 2: AB[h][m][i] (64x32): m<32: Re(W_d^{31-i}); m>=32: Im(W_d^{31-i}).
//   CB[h][i][k] (32x96): k<32: Toeplitz f[i-k] (k<=i else 0);
//                        k in [32,64): d=k-32:  qs_d*Re(W_d^{i+1});
//                        k in [64,96): d=k-64: -qs_d*Im(W_d^{i+1}).
__global__ __launch_bounds__(256) void fkprep_kernel(
        const float* __restrict__ a, const float* __restrict__ th,
        const float* __restrict__ bb, const float* __restrict__ cc,
        const float* __restrict__ x0, const float* __restrict__ W,
        __hip_bfloat16* __restrict__ Wb, unsigned* __restrict__ FKf,
        _Float16* __restrict__ AB, _Float16* __restrict__ CB,
        _Float16* __restrict__ WPh) {
    __shared__ float avs[32], tvs[32], qds[32], gxs[32], f_lds[32];
    int h = blockIdx.x;
    int t = threadIdx.x;
    const float T = 1.0f / (float)(L_ - 1);
    // W row cast (independent of everything else)
    Wb[(size_t)h * 512 + t]       = __float2bfloat16(W[(size_t)h * 512 + t]);
    Wb[(size_t)h * 512 + t + 256] = __float2bfloat16(W[(size_t)h * 512 + t + 256]);
    // phase 0: per-d params + WPh
    if (t < 32) {
        int d = t;
        float av = -fabsf(a[h * D2_ + d]);
        float tv = th[h * D2_ + d];
        avs[d] = av; tvs[d] = tv;
        qds[d] = bb[h * D2_ + d] * cc[h * D2_ + d];
        gxs[d] = 2.0f * cc[h * D2_ + d] * x0[h * D2_ + d];
        #pragma unroll
        for (int k = 0; k < 6; ++k) {
            float len = (float)(32 << k);        // 32 * 2^k steps
            float e2  = __expf(av * T * len);
            float an  = tv * T * len;
            WPh[((size_t)h * 6 + k) * 64 + d]      = (_Float16)(e2 * __cosf(an));
            WPh[((size_t)h * 6 + k) * 64 + 32 + d] = (_Float16)(e2 * __sinf(an));
        }
    }
    __syncthreads();
    // phase 1: fk recurrence
    int q4 = t & 3, lc = t >> 2;
    float z0 = T * (float)(lc * 32);
    float pr[8], pi[8], wr[8], wi[8], qd[8], gx[8];
    #pragma unroll
    for (int j = 0; j < 8; ++j) {
        int d = q4 * 8 + j;
        float aa = avs[d], tv = tvs[d];
        float e0 = __expf(aa * z0);
        pr[j] = e0 * __cosf(tv * z0);
        pi[j] = e0 * __sinf(tv * z0);
        float e1 = __expf(aa * T);
        wr[j] = e1 * __cosf(tv * T);
        wi[j] = e1 * __sinf(tv * T);
        qd[j] = qds[d];
        gx[j] = gxs[d];
    }
    for (int i = 0; i < 32; ++i) {
        float fa = 0.f, ka = 0.f;
        #pragma unroll
        for (int j = 0; j < 8; ++j) {
            fa = fmaf(qd[j], pr[j], fa);
            ka = fmaf(gx[j], pr[j], ka);
            float nr = fmaf(pr[j], wr[j], -(pi[j] * wi[j]));
            float ni = fmaf(pr[j], wi[j],  (pi[j] * wr[j]));
            pr[j] = nr; pi[j] = ni;
        }
        fa += __shfl_xor(fa, 1); fa += __shfl_xor(fa, 2);
        ka += __shfl_xor(ka, 1); ka += __shfl_xor(ka, 2);
        if (q4 == 0) {
            float fv = 2.0f * T * fa;
            FKf[(size_t)h * L_ + lc * 32 + i] = pack_bf16x2(fv, ka);
            if (lc == 0) f_lds[i] = fv;
        }
    }
    __syncthreads();
    // phase 2: operand matrices (fp16)
    for (int e = t; e < 64 * 32; e += 256) {
        int m = e >> 5, i = e & 31;
        int d = m & 31;
        float av = avs[d], tv = tvs[d];
        float z  = T * (float)(31 - i);
        float ex = __expf(av * z);
        float v  = (m < 32) ? ex * __cosf(tv * z) : ex * __sinf(tv * z);
        AB[(size_t)h * 2048 + e] = (_Float16)v;
    }
    for (int e = t; e < 32 * 96; e += 256) {
        int i = e / 96, k = e - i * 96;
        float v = 0.f;
        if (k < 32) {
            if (k <= i) v = f_lds[i - k];
        } else {
            int d = (k < 64) ? k - 32 : k - 64;
            float av = avs[d], tv = tvs[d];
            float qs = 2.0f * T * qds[d];
            float z  = T * (float)(i + 1);
            float ex = __expf(av * z);
            v = (k < 64) ? qs * ex * __cosf(tv * z) : -qs * ex * __sinf(tv * z);
        }
        CB[(size_t)h * 3072 + e] = (_Float16)v;
    }
}

// ---------------- scan_mfma (R4-proven): 2 waves per (b,h), fp16 MFMA + packed-fp16 scan ----
// R5's 2-batch-per-block variant spilled (~38MB scratch traffic) — reverted.
// Only change vs R4: __launch_bounds__(128, 8) → 16 blocks/CU resident
// (was 6 → 12-block cap; LDS 9.2KB and VGPR 40 both permit 16).
__global__ __launch_bounds__(128, 8) void scan_mfma_kernel(
        const float* __restrict__ u, const _Float16* __restrict__ AB,
        const _Float16* __restrict__ CB, const unsigned* __restrict__ WPh,
        const float* __restrict__ Dp, const unsigned* __restrict__ FKf,
        __hip_bfloat16* __restrict__ y) {
    __shared__ __align__(16) unsigned El[64 * EP];
    int wid = threadIdx.x >> 6, lane = threadIdx.x & 63;
    int h = blockIdx.x, b = blockIdx.y;
    int ln = lane & 15, qq = lane >> 4;
    const float* ug = u + (size_t)(b * H_ + h) * L_;

    // ---- U fragments (fp16), all 4 column-tiles (needed as M1 B-operand) ----
    half8 uf[4];
    #pragma unroll
    for (int nb = 0; nb < 4; ++nb) {
        const float* p = ug + (nb * 16 + ln) * 32 + qq * 8;
        float4 a0 = *(const float4*)p;
        float4 a1 = *(const float4*)(p + 4);
        unsigned* vp = (unsigned*)&uf[nb];
        vp[0] = pack_f16x2(a0.x, a0.y);
        vp[1] = pack_f16x2(a0.z, a0.w);
        vp[2] = pack_f16x2(a1.x, a1.y);
        vp[3] = pack_f16x2(a1.z, a1.w);
    }

    // ---- M1: this wave's Er/Ei rows (d-half) ----
    const _Float16* ABh = AB + (size_t)h * 2048;
    int j0 = wid * 8 + qq * 2;
    #pragma unroll
    for (int e = 0; e < 2; ++e) {       // e=0: Re rows, e=1: Im rows
        half8 af = *(const half8*)&ABh[(e * 32 + wid * 16 + ln) * 32 + qq * 8];
        #pragma unroll
        for (int nb = 0; nb < 4; ++nb) {
            float4v acc = (float4v){0.f, 0.f, 0.f, 0.f};
            acc = __builtin_amdgcn_mfma_f32_16x16x32_f16(af, uf[nb], acc, 0, 0, 0);
            unsigned p0 = pack_f16x2(acc[0], acc[1]);
            unsigned p1 = pack_f16x2(acc[2], acc[3]);
            *(uint2*)&El[(nb * 16 + ln) * EP + e * 16 + j0] = make_uint2(p0, p1);
        }
    }
    // own-wave write->read: DS ops drain, no cross-wave dependency yet
    asm volatile("s_waitcnt lgkmcnt(0)" ::: "memory");
    __builtin_amdgcn_sched_barrier(0);

    // ---- packed-fp16 scan over chunks (lane = c), own 8 pairs ----
    int c = lane;
    unsigned sr[8], si[8];
    {
        const unsigned* rp = &El[c * EP + wid * 8];
        uint4 r0 = *(const uint4*)rp;
        uint4 r1 = *(const uint4*)(rp + 4);
        uint4 i0 = *(const uint4*)(rp + 16);
        uint4 i1 = *(const uint4*)(rp + 20);
        sr[0]=r0.x; sr[1]=r0.y; sr[2]=r0.z; sr[3]=r0.w;
        sr[4]=r1.x; sr[5]=r1.y; sr[6]=r1.z; sr[7]=r1.w;
        si[0]=i0.x; si[1]=i0.y; si[2]=i0.z; si[3]=i0.w;
        si[4]=i1.x; si[5]=i1.y; si[6]=i1.z; si[7]=i1.w;
    }
    const unsigned* mpb = WPh + (size_t)h * 6 * 32;
    #pragma unroll
    for (int st = 0; st < 6; ++st) {
        int off = 1 << st;
        int src = (c - off) & 63;
        bool act = c >= off;
        const unsigned* mp = mpb + st * 32 + wid * 8;
        #pragma unroll
        for (int jj = 0; jj < 8; ++jj) {
            unsigned prp = (unsigned)__shfl((int)sr[jj], src);
            unsigned pip = (unsigned)__shfl((int)si[jj], src);
            if (!act) { prp = 0u; pip = 0u; }
            unsigned mru = mp[jj];
            unsigned miu = mp[16 + jj];
            unsigned min_ = miu ^ 0x80008000u;          // -Mi via sign flip
            half2v pr = *(half2v*)&prp, pi = *(half2v*)&pip;
            half2v Mr = *(half2v*)&mru, Mi = *(half2v*)&miu, Mni = *(half2v*)&min_;
            half2v s_r = *(half2v*)&sr[jj], s_i = *(half2v*)&si[jj];
            half2v nr = pk_fma16(pr, Mr, pk_fma16(pi, Mni, s_r));
            half2v ni = pk_fma16(pr, Mi, pk_fma16(pi, Mr,  s_i));
            sr[jj] = *(unsigned*)&nr; si[jj] = *(unsigned*)&ni;
        }
    }
    {   // exclusive shift: carry entering chunk c = S_{c-1}; lane 0 -> 0
        int srcm1 = (c - 1) & 63;
        #pragma unroll
        for (int jj = 0; jj < 8; ++jj) {
            unsigned a0 = (unsigned)__shfl((int)sr[jj], srcm1);
            unsigned b0 = (unsigned)__shfl((int)si[jj], srcm1);
            if (c == 0) { a0 = 0u; b0 = 0u; }
            sr[jj] = a0; si[jj] = b0;
        }
    }
    {   // carries back to same El slots
        unsigned* wp = &El[c * EP + wid * 8];
        *(uint4*)wp        = make_uint4(sr[0], sr[1], sr[2], sr[3]);
        *(uint4*)(wp + 4)  = make_uint4(sr[4], sr[5], sr[6], sr[7]);
        *(uint4*)(wp + 16) = make_uint4(si[0], si[1], si[2], si[3]);
        *(uint4*)(wp + 20) = make_uint4(si[4], si[5], si[6], si[7]);
    }
    // prefetch FK for epilogue; latency hides under barrier + M2
    const unsigned* fgh = FKf + (size_t)h * L_;
    uint4 fkp[2][2];
    #pragma unroll
    for (int nbi = 0; nbi < 2; ++nbi) {
        int col = (2 * wid + nbi) * 16 + ln;
        fkp[nbi][0] = *(const uint4*)&fgh[col * 32 + qq * 4];
        fkp[nbi][1] = *(const uint4*)&fgh[col * 32 + 16 + qq * 4];
    }
    __syncthreads();

    // ---- M2: y_pre = [T_f | Qr | -Qi] @ [U; Sr; Si], this wave's 2 col-tiles ----
    const _Float16* CBh = CB + (size_t)h * 3072;
    float4v acc2[2][2];
    #pragma unroll
    for (int mb = 0; mb < 2; ++mb)
        #pragma unroll
        for (int nbi = 0; nbi < 2; ++nbi)
            acc2[mb][nbi] = (float4v){0.f, 0.f, 0.f, 0.f};
    #pragma unroll
    for (int ks = 0; ks < 3; ++ks) {
        half8 a2[2];
        a2[0] = *(const half8*)&CBh[(ln)      * 96 + ks * 32 + qq * 8];
        a2[1] = *(const half8*)&CBh[(16 + ln) * 96 + ks * 32 + qq * 8];
        #pragma unroll
        for (int nbi = 0; nbi < 2; ++nbi) {
            int col = (2 * wid + nbi) * 16 + ln;
            half8 bfv;
            if (ks == 0) bfv = uf[2 * wid + nbi];
            else {
                int off = (ks == 1) ? 0 : 16;
                bfv = *(const half8*)&El[col * EP + off + qq * 4];
            }
            acc2[0][nbi] = __builtin_amdgcn_mfma_f32_16x16x32_f16(a2[0], bfv, acc2[0][nbi], 0, 0, 0);
            acc2[1][nbi] = __builtin_amdgcn_mfma_f32_16x16x32_f16(a2[1], bfv, acc2[1][nbi], 0, 0, 0);
        }
    }

    // ---- epilogue: y = y_pre + c0*u + c1*f + k0, fast gelu, pack bf16 ----
    float f0; { f0 = unpack_bf16x2(fgh[0]).x; }
    float c0v = Dp[h] - 0.5f * f0;
    float c1v = -0.5f * ug[0];
    #pragma unroll
    for (int nbi = 0; nbi < 2; ++nbi) {
        int col = (2 * wid + nbi) * 16 + ln;
        #pragma unroll
        for (int mb = 0; mb < 2; ++mb) {
            int l0 = col * 32 + mb * 16 + qq * 4;
            float4 u4 = *(const float4*)(ug + l0);
            uint4 fkv = fkp[nbi][mb];
            float us[4] = {u4.x, u4.y, u4.z, u4.w};
            unsigned fs[4] = {fkv.x, fkv.y, fkv.z, fkv.w};
            float g[4];
            #pragma unroll
            for (int r = 0; r < 4; ++r) {
                float2 fk = unpack_bf16x2(fs[r]);
                float yv = acc2[mb][nbi][r] + fmaf(c0v, us[r], fmaf(c1v, fk.x, fk.y));
                g[r] = gelu_fast(yv);
            }
            uint2 yo;
            yo.x = pack_bf16x2(g[0], g[1]);
            yo.y = pack_bf16x2(g[2], g[3]);
            *(uint2*)((short*)y + (size_t)(b * H_ + h) * L_ + l0) = yo;
        }
    }
}

// ---------------- transpose y[b][f][l] -> yT[b][l][f] (bf16) ----------------
// XOR-swizzle the l-index with 8*(f>>3): removes the 8-way LDS read conflict
// (576*(t&7) ≡ 0 mod 64 made all col-groups alias one bank). Keeps uint4
// write contiguity (XOR in units of 8 elements) and 16B alignment.
__global__ __launch_bounds__(256) void transpose_y_kernel(
        const __hip_bfloat16* __restrict__ y, __hip_bfloat16* __restrict__ yT) {
    __shared__ short tile[64][72];
    int l0 = blockIdx.x * 64, f0 = blockIdx.y * 64, b = blockIdx.z;
    int t = threadIdx.x;
    int row = t >> 3, col8 = (t & 7) * 8;
    const short* yg = (const short*)y + (size_t)b * H_ * L_;
    #pragma unroll
    for (int r2 = 0; r2 < 64; r2 += 32) {
        int fr = row + r2;
        *(uint4*)&tile[fr][col8 ^ (8 * ((fr >> 3) & 7))] =
            *(const uint4*)&yg[(size_t)(f0 + fr) * L_ + l0 + col8];
    }
    __syncthreads();
    short* og = (short*)yT + (size_t)b * L_ * H_;
    #pragma unroll
    for (int r2 = 0; r2 < 64; r2 += 32) {
        int lrow = row + r2;
        short v[8];
        #pragma unroll
        for (int j = 0; j < 8; ++j) {
            int f = col8 + j;
            v[j] = tile[f][lrow ^ (8 * ((f >> 3) & 7))];
        }
        *(uint4*)&og[(size_t)(l0 + lrow) * H_ + f0 + col8] = *(uint4*)v;
    }
}

// ---------------- gemm: out[b,h,l] = sum_f W[h,f] * yT[b,l,f] + bias[h] ----------------
// 64x128 tile, grid 1024 blocks (4/CU, 16 waves/CU).
__global__ __launch_bounds__(256) void gemm_kernel(
        const __hip_bfloat16* __restrict__ Wb, const __hip_bfloat16* __restrict__ yT,
        const float* __restrict__ bias, float* __restrict__ out) {
    __shared__ __align__(16) short As[64 * 32];
    __shared__ __align__(16) short Bs[128 * 32];
    int l0 = blockIdx.x * 128;
    int h0 = blockIdx.y * 64;
    int b  = blockIdx.z;
    int t    = threadIdx.x;
    int lane = t & 63, wave = t >> 6;
    int m_off = (wave >> 1) * 32, n_off = (wave & 1) * 64;
    int quad = lane >> 4, ln = lane & 15;

    float4v acc[2][4];
    #pragma unroll
    for (int mt = 0; mt < 2; ++mt)
        #pragma unroll
        for (int nt = 0; nt < 4; ++nt)
            acc[mt][nt] = (float4v){0.f, 0.f, 0.f, 0.f};

    const short* Wg = (const short*)Wb;
    const short* Yg = (const short*)(yT + (size_t)b * L_ * H_);

    int r  = t >> 2;       // 0..63
    int qd = t & 3;

    for (int kt = 0; kt < 16; ++kt) {
        int k0 = kt * 32;
        load_lds16(Wg + (h0 + r) * 512 + k0 + qd * 8, &As[t * 8]);
        load_lds16(Yg + (size_t)(l0 + r)      * 512 + k0 + qd * 8, &Bs[t * 8]);
        load_lds16(Yg + (size_t)(l0 + r + 64) * 512 + k0 + qd * 8, &Bs[(t + 256) * 8]);
        __syncthreads();

        short8 af[2], bf[4];
        #pragma unroll
        for (int mt = 0; mt < 2; ++mt)
            af[mt] = *(const short8*)&As[(m_off + mt * 16 + ln) * 32 + quad * 8];
        #pragma unroll
        for (int nt = 0; nt < 4; ++nt)
            bf[nt] = *(const short8*)&Bs[(n_off + nt * 16 + ln) * 32 + quad * 8];
        #pragma unroll
        for (int mt = 0; mt < 2; ++mt)
            #pragma unroll
            for (int nt = 0; nt < 4; ++nt)
                acc[mt][nt] = __builtin_amdgcn_mfma_f32_16x16x32_bf16(
                    af[mt], bf[nt], acc[mt][nt], 0, 0, 0);
        __syncthreads();
    }

    #pragma unroll
    for (int mt = 0; mt < 2; ++mt) {
        #pragma unroll
        for (int nt = 0; nt < 4; ++nt) {
            int hh = h0 + m_off + mt * 16 + quad * 4;
            int ll = l0 + n_off + nt * 16 + ln;
            #pragma unroll
            for (int r2 = 0; r2 < 4; ++r2)
                out[((size_t)(b * H_ + hh + r2)) * L_ + ll] = acc[mt][nt][r2] + bias[hh + r2];
        }
    }
}

extern "C" void kernel_launch(void* const* d_in, const int* in_sizes, int n_in,
                              void* d_out, int out_size, void* d_ws, size_t ws_size,
                              hipStream_t stream) {
    const float* u    = (const float*)d_in[0];
    const float* a    = (const float*)d_in[1];
    const float* th   = (const float*)d_in[2];
    const float* bb   = (const float*)d_in[3];
    const float* cc   = (const float*)d_in[4];
    const float* x0   = (const float*)d_in[5];
    const float* Dp   = (const float*)d_in[6];
    const float* W    = (const float*)d_in[7];
    const float* bias = (const float*)d_in[8];
    float* out = (float*)d_out;
    char* ws = (char*)d_ws;

    // layout: FKf 4M @0 | yT 16M @4M | y 16M @20M | Wb 0.5M @36M | AB 2M @37M |
    //         CB 3M @39M | WPh fp16 384KB @42M
    unsigned*       FKf = (unsigned*)ws;
    __hip_bfloat16* yT  = (__hip_bfloat16*)(ws + (4ull  << 20));
    __hip_bfloat16* y   = (__hip_bfloat16*)(ws + (20ull << 20));
    __hip_bfloat16* Wb  = (__hip_bfloat16*)(ws + (36ull << 20));
    _Float16*       AB  = (_Float16*)(ws + (37ull << 20));
    _Float16*       CB  = (_Float16*)(ws + (39ull << 20));
    _Float16*       WPh = (_Float16*)(ws + (42ull << 20));

    hipLaunchKernelGGL(fkprep_kernel,     dim3(H_),        dim3(256), 0, stream,
                       a, th, bb, cc, x0, W, Wb, FKf, AB, CB, WPh);
    hipLaunchKernelGGL(scan_mfma_kernel,  dim3(H_, B_),    dim3(128), 0, stream,
                       u, AB, CB, (const unsigned*)WPh, Dp, FKf, y);
    hipLaunchKernelGGL(transpose_y_kernel,dim3(32, 8, 8),  dim3(256), 0, stream, y, yT);
    hipLaunchKernelGGL(gemm_kernel,       dim3(16, 8, 8),  dim3(256), 0, stream,
                       Wb, yT, bias, out);
}

// Round 7
// 165.676 us; speedup vs baseline: 1.1737x; 1.0223x over previous
//
#include <hip/hip_runtime.h>
#include <hip/hip_bf16.h>

#define B_  8
#define H_  512
#define L_  2048
#define D2_ 32
#define NC_ 64
#define LC_ 32    // L_/NC_
#define EP  36    // E_lds row pitch in u32 (16B-aligned rows)

typedef __attribute__((ext_vector_type(8))) short short8;     // 8 bf16 (4 VGPRs)
typedef __attribute__((ext_vector_type(8))) _Float16 half8;   // 8 fp16 (4 VGPRs)
typedef __attribute__((ext_vector_type(2))) _Float16 half2v;  // packed fp16 (v_pk_*)
typedef __attribute__((ext_vector_type(4))) float float4v;    // 4 fp32 acc

__device__ __forceinline__ half2v pk_fma16(half2v a, half2v b, half2v c) {
    return __builtin_elementwise_fma(a, b, c);
}

// tanh-form GELU: max |err| vs exact ~3e-4, far below bf16 y-storage ulp.
__device__ __forceinline__ float gelu_fast(float x) {
    float q = x * fmaf(0.044715f, x * x, 1.0f);
    float s = __expf(-1.5957691216057308f * q);   // e^{-2*0.79788456*q}
    return __fdividef(x, 1.0f + s);               // x * sigmoid(2w)
}

__device__ __forceinline__ unsigned pack_bf16x2(float x, float y) {
    __hip_bfloat162 p = __float22bfloat162_rn(make_float2(x, y));
    return *(unsigned*)&p;
}
__device__ __forceinline__ float2 unpack_bf16x2(unsigned v) {
    __hip_bfloat162 p = *(__hip_bfloat162*)&v;
    return __bfloat1622float2(p);
}
__device__ __forceinline__ unsigned pack_f16x2(float x, float y) {
    auto v = __builtin_amdgcn_cvt_pkrtz(x, y);    // v_cvt_pkrtz_f16_f32
    return *(unsigned*)&v;
}

__device__ __forceinline__ void load_lds16(const void* g, void* l) {
    __builtin_amdgcn_global_load_lds((const __attribute__((address_space(1))) unsigned int*)g,
                                     (__attribute__((address_space(3))) unsigned int*)l, 16, 0, 0);
}

// ---------------- fkprep: params + fk (f,k0) + MFMA operands + W-cast, 1 block/h ----
__global__ __launch_bounds__(256) void fkprep_kernel(
        const float* __restrict__ a, const float* __restrict__ th,
        const float* __restrict__ bb, const float* __restrict__ cc,
        const float* __restrict__ x0, const float* __restrict__ W,
        __hip_bfloat16* __restrict__ Wb, unsigned* __restrict__ FKf,
        _Float16* __restrict__ AB, _Float16* __restrict__ CB,
        _Float16* __restrict__ WPh) {
    __shared__ float avs[32], tvs[32], qds[32], gxs[32], f_lds[32];
    int h = blockIdx.x;
    int t = threadIdx.x;
    const float T = 1.0f / (float)(L_ - 1);
    // W row cast (independent of everything else)
    Wb[(size_t)h * 512 + t]       = __float2bfloat16(W[(size_t)h * 512 + t]);
    Wb[(size_t)h * 512 + t + 256] = __float2bfloat16(W[(size_t)h * 512 + t + 256]);
    // phase 0: per-d params + WPh
    if (t < 32) {
        int d = t;
        float av = -fabsf(a[h * D2_ + d]);
        float tv = th[h * D2_ + d];
        avs[d] = av; tvs[d] = tv;
        qds[d] = bb[h * D2_ + d] * cc[h * D2_ + d];
        gxs[d] = 2.0f * cc[h * D2_ + d] * x0[h * D2_ + d];
        #pragma unroll
        for (int k = 0; k < 6; ++k) {
            float len = (float)(32 << k);        // 32 * 2^k steps
            float e2  = __expf(av * T * len);
            float an  = tv * T * len;
            WPh[((size_t)h * 6 + k) * 64 + d]      = (_Float16)(e2 * __cosf(an));
            WPh[((size_t)h * 6 + k) * 64 + 32 + d] = (_Float16)(e2 * __sinf(an));
        }
    }
    __syncthreads();
    // phase 1: fk recurrence
    int q4 = t & 3, lc = t >> 2;
    float z0 = T * (float)(lc * 32);
    float pr[8], pi[8], wr[8], wi[8], qd[8], gx[8];
    #pragma unroll
    for (int j = 0; j < 8; ++j) {
        int d = q4 * 8 + j;
        float aa = avs[d], tv = tvs[d];
        float e0 = __expf(aa * z0);
        pr[j] = e0 * __cosf(tv * z0);
        pi[j] = e0 * __sinf(tv * z0);
        float e1 = __expf(aa * T);
        wr[j] = e1 * __cosf(tv * T);
        wi[j] = e1 * __sinf(tv * T);
        qd[j] = qds[d];
        gx[j] = gxs[d];
    }
    for (int i = 0; i < 32; ++i) {
        float fa = 0.f, ka = 0.f;
        #pragma unroll
        for (int j = 0; j < 8; ++j) {
            fa = fmaf(qd[j], pr[j], fa);
            ka = fmaf(gx[j], pr[j], ka);
            float nr = fmaf(pr[j], wr[j], -(pi[j] * wi[j]));
            float ni = fmaf(pr[j], wi[j],  (pi[j] * wr[j]));
            pr[j] = nr; pi[j] = ni;
        }
        fa += __shfl_xor(fa, 1); fa += __shfl_xor(fa, 2);
        ka += __shfl_xor(ka, 1); ka += __shfl_xor(ka, 2);
        if (q4 == 0) {
            float fv = 2.0f * T * fa;
            FKf[(size_t)h * L_ + lc * 32 + i] = pack_bf16x2(fv, ka);
            if (lc == 0) f_lds[i] = fv;
        }
    }
    __syncthreads();
    // phase 2: operand matrices (fp16)
    for (int e = t; e < 64 * 32; e += 256) {
        int m = e >> 5, i = e & 31;
        int d = m & 31;
        float av = avs[d], tv = tvs[d];
        float z  = T * (float)(31 - i);
        float ex = __expf(av * z);
        float v  = (m < 32) ? ex * __cosf(tv * z) : ex * __sinf(tv * z);
        AB[(size_t)h * 2048 + e] = (_Float16)v;
    }
    for (int e = t; e < 32 * 96; e += 256) {
        int i = e / 96, k = e - i * 96;
        float v = 0.f;
        if (k < 32) {
            if (k <= i) v = f_lds[i - k];
        } else {
            int d = (k < 64) ? k - 32 : k - 64;
            float av = avs[d], tv = tvs[d];
            float qs = 2.0f * T * qds[d];
            float z  = T * (float)(i + 1);
            float ex = __expf(av * z);
            v = (k < 64) ? qs * ex * __cosf(tv * z) : -qs * ex * __sinf(tv * z);
        }
        CB[(size_t)h * 3072 + e] = (_Float16)v;
    }
}

// ---------------- scan_mfma (R4-proven): 2 waves per (b,h), fp16 MFMA + packed-fp16 scan ----
// launch_bounds (128,6): R6's (128,8) forced VGPR 40->32 and spilled (~14MB
// scratch writes, scan 46->50.7us). 6 gives VGPR 40, no spill — proven R4.
__global__ __launch_bounds__(128, 6) void scan_mfma_kernel(
        const float* __restrict__ u, const _Float16* __restrict__ AB,
        const _Float16* __restrict__ CB, const unsigned* __restrict__ WPh,
        const float* __restrict__ Dp, const unsigned* __restrict__ FKf,
        __hip_bfloat16* __restrict__ y) {
    __shared__ __align__(16) unsigned El[64 * EP];
    int wid = threadIdx.x >> 6, lane = threadIdx.x & 63;
    int h = blockIdx.x, b = blockIdx.y;
    int ln = lane & 15, qq = lane >> 4;
    const float* ug = u + (size_t)(b * H_ + h) * L_;

    // ---- U fragments (fp16), all 4 column-tiles (needed as M1 B-operand) ----
    half8 uf[4];
    #pragma unroll
    for (int nb = 0; nb < 4; ++nb) {
        const float* p = ug + (nb * 16 + ln) * 32 + qq * 8;
        float4 a0 = *(const float4*)p;
        float4 a1 = *(const float4*)(p + 4);
        unsigned* vp = (unsigned*)&uf[nb];
        vp[0] = pack_f16x2(a0.x, a0.y);
        vp[1] = pack_f16x2(a0.z, a0.w);
        vp[2] = pack_f16x2(a1.x, a1.y);
        vp[3] = pack_f16x2(a1.z, a1.w);
    }

    // ---- M1: this wave's Er/Ei rows (d-half) ----
    const _Float16* ABh = AB + (size_t)h * 2048;
    int j0 = wid * 8 + qq * 2;
    #pragma unroll
    for (int e = 0; e < 2; ++e) {       // e=0: Re rows, e=1: Im rows
        half8 af = *(const half8*)&ABh[(e * 32 + wid * 16 + ln) * 32 + qq * 8];
        #pragma unroll
        for (int nb = 0; nb < 4; ++nb) {
            float4v acc = (float4v){0.f, 0.f, 0.f, 0.f};
            acc = __builtin_amdgcn_mfma_f32_16x16x32_f16(af, uf[nb], acc, 0, 0, 0);
            unsigned p0 = pack_f16x2(acc[0], acc[1]);
            unsigned p1 = pack_f16x2(acc[2], acc[3]);
            *(uint2*)&El[(nb * 16 + ln) * EP + e * 16 + j0] = make_uint2(p0, p1);
        }
    }
    // own-wave write->read: DS ops drain, no cross-wave dependency yet
    asm volatile("s_waitcnt lgkmcnt(0)" ::: "memory");
    __builtin_amdgcn_sched_barrier(0);

    // ---- packed-fp16 scan over chunks (lane = c), own 8 pairs ----
    int c = lane;
    unsigned sr[8], si[8];
    {
        const unsigned* rp = &El[c * EP + wid * 8];
        uint4 r0 = *(const uint4*)rp;
        uint4 r1 = *(const uint4*)(rp + 4);
        uint4 i0 = *(const uint4*)(rp + 16);
        uint4 i1 = *(const uint4*)(rp + 20);
        sr[0]=r0.x; sr[1]=r0.y; sr[2]=r0.z; sr[3]=r0.w;
        sr[4]=r1.x; sr[5]=r1.y; sr[6]=r1.z; sr[7]=r1.w;
        si[0]=i0.x; si[1]=i0.y; si[2]=i0.z; si[3]=i0.w;
        si[4]=i1.x; si[5]=i1.y; si[6]=i1.z; si[7]=i1.w;
    }
    const unsigned* mpb = WPh + (size_t)h * 6 * 32;
    #pragma unroll
    for (int st = 0; st < 6; ++st) {
        int off = 1 << st;
        int src = (c - off) & 63;
        bool act = c >= off;
        const unsigned* mp = mpb + st * 32 + wid * 8;
        #pragma unroll
        for (int jj = 0; jj < 8; ++jj) {
            unsigned prp = (unsigned)__shfl((int)sr[jj], src);
            unsigned pip = (unsigned)__shfl((int)si[jj], src);
            if (!act) { prp = 0u; pip = 0u; }
            unsigned mru = mp[jj];
            unsigned miu = mp[16 + jj];
            unsigned min_ = miu ^ 0x80008000u;          // -Mi via sign flip
            half2v pr = *(half2v*)&prp, pi = *(half2v*)&pip;
            half2v Mr = *(half2v*)&mru, Mi = *(half2v*)&miu, Mni = *(half2v*)&min_;
            half2v s_r = *(half2v*)&sr[jj], s_i = *(half2v*)&si[jj];
            half2v nr = pk_fma16(pr, Mr, pk_fma16(pi, Mni, s_r));
            half2v ni = pk_fma16(pr, Mi, pk_fma16(pi, Mr,  s_i));
            sr[jj] = *(unsigned*)&nr; si[jj] = *(unsigned*)&ni;
        }
    }
    {   // exclusive shift: carry entering chunk c = S_{c-1}; lane 0 -> 0
        int srcm1 = (c - 1) & 63;
        #pragma unroll
        for (int jj = 0; jj < 8; ++jj) {
            unsigned a0 = (unsigned)__shfl((int)sr[jj], srcm1);
            unsigned b0 = (unsigned)__shfl((int)si[jj], srcm1);
            if (c == 0) { a0 = 0u; b0 = 0u; }
            sr[jj] = a0; si[jj] = b0;
        }
    }
    {   // carries back to same El slots
        unsigned* wp = &El[c * EP + wid * 8];
        *(uint4*)wp        = make_uint4(sr[0], sr[1], sr[2], sr[3]);
        *(uint4*)(wp + 4)  = make_uint4(sr[4], sr[5], sr[6], sr[7]);
        *(uint4*)(wp + 16) = make_uint4(si[0], si[1], si[2], si[3]);
        *(uint4*)(wp + 20) = make_uint4(si[4], si[5], si[6], si[7]);
    }
    // prefetch FK for epilogue; latency hides under barrier + M2
    const unsigned* fgh = FKf + (size_t)h * L_;
    uint4 fkp[2][2];
    #pragma unroll
    for (int nbi = 0; nbi < 2; ++nbi) {
        int col = (2 * wid + nbi) * 16 + ln;
        fkp[nbi][0] = *(const uint4*)&fgh[col * 32 + qq * 4];
        fkp[nbi][1] = *(const uint4*)&fgh[col * 32 + 16 + qq * 4];
    }
    __syncthreads();

    // ---- M2: y_pre = [T_f | Qr | -Qi] @ [U; Sr; Si], this wave's 2 col-tiles ----
    const _Float16* CBh = CB + (size_t)h * 3072;
    float4v acc2[2][2];
    #pragma unroll
    for (int mb = 0; mb < 2; ++mb)
        #pragma unroll
        for (int nbi = 0; nbi < 2; ++nbi)
            acc2[mb][nbi] = (float4v){0.f, 0.f, 0.f, 0.f};
    #pragma unroll
    for (int ks = 0; ks < 3; ++ks) {
        half8 a2[2];
        a2[0] = *(const half8*)&CBh[(ln)      * 96 + ks * 32 + qq * 8];
        a2[1] = *(const half8*)&CBh[(16 + ln) * 96 + ks * 32 + qq * 8];
        #pragma unroll
        for (int nbi = 0; nbi < 2; ++nbi) {
            int col = (2 * wid + nbi) * 16 + ln;
            half8 bfv;
            if (ks == 0) bfv = uf[2 * wid + nbi];
            else {
                int off = (ks == 1) ? 0 : 16;
                bfv = *(const half8*)&El[col * EP + off + qq * 4];
            }
            acc2[0][nbi] = __builtin_amdgcn_mfma_f32_16x16x32_f16(a2[0], bfv, acc2[0][nbi], 0, 0, 0);
            acc2[1][nbi] = __builtin_amdgcn_mfma_f32_16x16x32_f16(a2[1], bfv, acc2[1][nbi], 0, 0, 0);
        }
    }

    // ---- epilogue: y = y_pre + c0*u + c1*f + k0, fast gelu, pack bf16 ----
    float f0; { f0 = unpack_bf16x2(fgh[0]).x; }
    float c0v = Dp[h] - 0.5f * f0;
    float c1v = -0.5f * ug[0];
    #pragma unroll
    for (int nbi = 0; nbi < 2; ++nbi) {
        int col = (2 * wid + nbi) * 16 + ln;
        #pragma unroll
        for (int mb = 0; mb < 2; ++mb) {
            int l0 = col * 32 + mb * 16 + qq * 4;
            float4 u4 = *(const float4*)(ug + l0);
            uint4 fkv = fkp[nbi][mb];
            float us[4] = {u4.x, u4.y, u4.z, u4.w};
            unsigned fs[4] = {fkv.x, fkv.y, fkv.z, fkv.w};
            float g[4];
            #pragma unroll
            for (int r = 0; r < 4; ++r) {
                float2 fk = unpack_bf16x2(fs[r]);
                float yv = acc2[mb][nbi][r] + fmaf(c0v, us[r], fmaf(c1v, fk.x, fk.y));
                g[r] = gelu_fast(yv);
            }
            uint2 yo;
            yo.x = pack_bf16x2(g[0], g[1]);
            yo.y = pack_bf16x2(g[2], g[3]);
            *(uint2*)((short*)y + (size_t)(b * H_ + h) * L_ + l0) = yo;
        }
    }
}

// ---------------- gemm (transpose fused): out[b,h,l] = sum_f W[h,f]*y[b,f,l] + bias ----
// B-operand read DIRECTLY from y[b][f][l] (no yT, no transpose kernel):
// per K-step, thread (fp=t&15, n8=t>>4) loads 8 l of rows f0+2fp and f0+2fp+1
// (coalesced along l), packs the (f,f+1) bf16 pair per l into one u32 (= the
// k-contiguous pair MFMA wants), ds_write_b32 into Bs[l][16 pairs] with a
// 4-pair XOR swizzle ((l>>2)&3)<<2 -> write conflicts 2-way (free, m136).
// Fragment read: ds_read_b128 at pair-idx qq*4^xw(l); since both are multiples
// of 4, (A^X)+i == (A+i)^X, so the 4 u32 un-XOR to pairs qq*4..qq*4+3 = k 8qq..8qq+7,
// byte-identical to the old Bs short8 layout. A-path and epilogue unchanged.
// Grid x=h-tile so the 8 blocks sharing one y l-slice dispatch adjacently (L2 reuse).
__global__ __launch_bounds__(256) void gemm_kernel(
        const __hip_bfloat16* __restrict__ Wb, const __hip_bfloat16* __restrict__ y,
        const float* __restrict__ bias, float* __restrict__ out) {
    __shared__ __align__(16) short    As[64 * 32];
    __shared__ __align__(16) unsigned Bs[128 * 16];
    int h0 = blockIdx.x * 64;
    int l0 = blockIdx.y * 128;
    int b  = blockIdx.z;
    int t    = threadIdx.x;
    int lane = t & 63, wave = t >> 6;
    int m_off = (wave >> 1) * 32, n_off = (wave & 1) * 64;
    int quad = lane >> 4, ln = lane & 15;

    float4v acc[2][4];
    #pragma unroll
    for (int mt = 0; mt < 2; ++mt)
        #pragma unroll
        for (int nt = 0; nt < 4; ++nt)
            acc[mt][nt] = (float4v){0.f, 0.f, 0.f, 0.f};

    const short* Wg = (const short*)Wb;
    const short* Yg = (const short*)y + (size_t)b * 512 * L_;   // [f][l], f = C*H

    int r  = t >> 2;       // 0..63 (A staging)
    int qd = t & 3;
    int fp = t & 15;       // B staging: f-pair 0..15
    int n8 = t >> 4;       // B staging: l-octet 0..15

    for (int kt = 0; kt < 16; ++kt) {
        int k0 = kt * 32;
        load_lds16(Wg + (h0 + r) * 512 + k0 + qd * 8, &As[t * 8]);
        // B: transposing reg-stage from y
        const short* ypa = Yg + (size_t)(k0 + 2 * fp) * L_ + l0 + n8 * 8;
        uint4 ya = *(const uint4*)ypa;
        uint4 yb = *(const uint4*)(ypa + L_);
        unsigned au[4] = {ya.x, ya.y, ya.z, ya.w};
        unsigned bu[4] = {yb.x, yb.y, yb.z, yb.w};
        unsigned pa[8];
        #pragma unroll
        for (int i2 = 0; i2 < 4; ++i2) {
            pa[2 * i2]     = (au[i2] & 0xFFFFu) | (bu[i2] << 16);
            pa[2 * i2 + 1] = (au[i2] >> 16)     | (bu[i2] & 0xFFFF0000u);
        }
        #pragma unroll
        for (int i = 0; i < 8; ++i) {
            int n = n8 * 8 + i;
            Bs[n * 16 + (fp ^ (((n >> 2) & 3) << 2))] = pa[i];
        }
        __syncthreads();

        short8 af[2], bf[4];
        #pragma unroll
        for (int mt = 0; mt < 2; ++mt)
            af[mt] = *(const short8*)&As[(m_off + mt * 16 + ln) * 32 + quad * 8];
        #pragma unroll
        for (int nt = 0; nt < 4; ++nt) {
            int n = n_off + nt * 16 + ln;
            bf[nt] = *(const short8*)&Bs[n * 16 + ((quad * 4) ^ (((n >> 2) & 3) << 2))];
        }
        #pragma unroll
        for (int mt = 0; mt < 2; ++mt)
            #pragma unroll
            for (int nt = 0; nt < 4; ++nt)
                acc[mt][nt] = __builtin_amdgcn_mfma_f32_16x16x32_bf16(
                    af[mt], bf[nt], acc[mt][nt], 0, 0, 0);
        __syncthreads();
    }

    #pragma unroll
    for (int mt = 0; mt < 2; ++mt) {
        #pragma unroll
        for (int nt = 0; nt < 4; ++nt) {
            int hh = h0 + m_off + mt * 16 + quad * 4;
            int ll = l0 + n_off + nt * 16 + ln;
            #pragma unroll
            for (int r2 = 0; r2 < 4; ++r2)
                out[((size_t)(b * H_ + hh + r2)) * L_ + ll] = acc[mt][nt][r2] + bias[hh + r2];
        }
    }
}

extern "C" void kernel_launch(void* const* d_in, const int* in_sizes, int n_in,
                              void* d_out, int out_size, void* d_ws, size_t ws_size,
                              hipStream_t stream) {
    const float* u    = (const float*)d_in[0];
    const float* a    = (const float*)d_in[1];
    const float* th   = (const float*)d_in[2];
    const float* bb   = (const float*)d_in[3];
    const float* cc   = (const float*)d_in[4];
    const float* x0   = (const float*)d_in[5];
    const float* Dp   = (const float*)d_in[6];
    const float* W    = (const float*)d_in[7];
    const float* bias = (const float*)d_in[8];
    float* out = (float*)d_out;
    char* ws = (char*)d_ws;

    // layout: FKf 4M @0 | y 16M @20M | Wb 0.5M @36M | AB 2M @37M |
    //         CB 3M @39M | WPh fp16 384KB @42M   (yT + transpose kernel removed)
    unsigned*       FKf = (unsigned*)ws;
    __hip_bfloat16* y   = (__hip_bfloat16*)(ws + (20ull << 20));
    __hip_bfloat16* Wb  = (__hip_bfloat16*)(ws + (36ull << 20));
    _Float16*       AB  = (_Float16*)(ws + (37ull << 20));
    _Float16*       CB  = (_Float16*)(ws + (39ull << 20));
    _Float16*       WPh = (_Float16*)(ws + (42ull << 20));

    hipLaunchKernelGGL(fkprep_kernel,     dim3(H_),        dim3(256), 0, stream,
                       a, th, bb, cc, x0, W, Wb, FKf, AB, CB, WPh);
    hipLaunchKernelGGL(scan_mfma_kernel,  dim3(H_, B_),    dim3(128), 0, stream,
                       u, AB, CB, (const unsigned*)WPh, Dp, FKf, y);
    hipLaunchKernelGGL(gemm_kernel,       dim3(8, 16, 8),  dim3(256), 0, stream,
                       Wb, y, bias, out);
}

// Round 8
// 163.756 us; speedup vs baseline: 1.1875x; 1.0117x over previous
//
#include <hip/hip_runtime.h>
#include <hip/hip_bf16.h>

#define B_  8
#define H_  512
#define L_  2048
#define D2_ 32
#define NC_ 64
#define LC_ 32    // L_/NC_
#define EP  36    // E_lds row pitch in u32 (16B-aligned rows)

typedef __attribute__((ext_vector_type(8))) short short8;     // 8 bf16 (4 VGPRs)
typedef __attribute__((ext_vector_type(8))) _Float16 half8;   // 8 fp16 (4 VGPRs)
typedef __attribute__((ext_vector_type(2))) _Float16 half2v;  // packed fp16 (v_pk_*)
typedef __attribute__((ext_vector_type(4))) float float4v;    // 4 fp32 acc

__device__ __forceinline__ half2v pk_fma16(half2v a, half2v b, half2v c) {
    return __builtin_elementwise_fma(a, b, c);
}

// tanh-form GELU: max |err| vs exact ~3e-4, far below bf16 y-storage ulp.
__device__ __forceinline__ float gelu_fast(float x) {
    float q = x * fmaf(0.044715f, x * x, 1.0f);
    float s = __expf(-1.5957691216057308f * q);   // e^{-2*0.79788456*q}
    return __fdividef(x, 1.0f + s);               // x * sigmoid(2w)
}

__device__ __forceinline__ unsigned pack_bf16x2(float x, float y) {
    __hip_bfloat162 p = __float22bfloat162_rn(make_float2(x, y));
    return *(unsigned*)&p;
}
__device__ __forceinline__ float2 unpack_bf16x2(unsigned v) {
    __hip_bfloat162 p = *(__hip_bfloat162*)&v;
    return __bfloat1622float2(p);
}
__device__ __forceinline__ unsigned pack_f16x2(float x, float y) {
    auto v = __builtin_amdgcn_cvt_pkrtz(x, y);    // v_cvt_pkrtz_f16_f32
    return *(unsigned*)&v;
}

__device__ __forceinline__ void load_lds16(const void* g, void* l) {
    __builtin_amdgcn_global_load_lds((const __attribute__((address_space(1))) unsigned int*)g,
                                     (__attribute__((address_space(3))) unsigned int*)l, 16, 0, 0);
}

// ---------------- fkprep: params + fk (f,k0) + MFMA operands + W-cast, 1 block/h ----
// FKf now staged through LDS fk_all[i][lc] (conflict-free banks) and stored
// with 2 coalesced uint4/thread — the old direct store was 4B/lane at 128B
// stride (64 lines touched per instr, ~1M fragmented write requests total).
__global__ __launch_bounds__(256) void fkprep_kernel(
        const float* __restrict__ a, const float* __restrict__ th,
        const float* __restrict__ bb, const float* __restrict__ cc,
        const float* __restrict__ x0, const float* __restrict__ W,
        __hip_bfloat16* __restrict__ Wb, unsigned* __restrict__ FKf,
        _Float16* __restrict__ AB, _Float16* __restrict__ CB,
        _Float16* __restrict__ WPh) {
    __shared__ float avs[32], tvs[32], qds[32], gxs[32], f_lds[32];
    __shared__ unsigned fk_all[32 * 64];     // [i][lc]
    int h = blockIdx.x;
    int t = threadIdx.x;
    const float T = 1.0f / (float)(L_ - 1);
    // W row cast (independent of everything else)
    Wb[(size_t)h * 512 + t]       = __float2bfloat16(W[(size_t)h * 512 + t]);
    Wb[(size_t)h * 512 + t + 256] = __float2bfloat16(W[(size_t)h * 512 + t + 256]);
    // phase 0: per-d params + WPh
    if (t < 32) {
        int d = t;
        float av = -fabsf(a[h * D2_ + d]);
        float tv = th[h * D2_ + d];
        avs[d] = av; tvs[d] = tv;
        qds[d] = bb[h * D2_ + d] * cc[h * D2_ + d];
        gxs[d] = 2.0f * cc[h * D2_ + d] * x0[h * D2_ + d];
        #pragma unroll
        for (int k = 0; k < 6; ++k) {
            float len = (float)(32 << k);        // 32 * 2^k steps
            float e2  = __expf(av * T * len);
            float an  = tv * T * len;
            WPh[((size_t)h * 6 + k) * 64 + d]      = (_Float16)(e2 * __cosf(an));
            WPh[((size_t)h * 6 + k) * 64 + 32 + d] = (_Float16)(e2 * __sinf(an));
        }
    }
    __syncthreads();
    // phase 1: fk recurrence
    int q4 = t & 3, lc = t >> 2;
    float z0 = T * (float)(lc * 32);
    float pr[8], pi[8], wr[8], wi[8], qd[8], gx[8];
    #pragma unroll
    for (int j = 0; j < 8; ++j) {
        int d = q4 * 8 + j;
        float aa = avs[d], tv = tvs[d];
        float e0 = __expf(aa * z0);
        pr[j] = e0 * __cosf(tv * z0);
        pi[j] = e0 * __sinf(tv * z0);
        float e1 = __expf(aa * T);
        wr[j] = e1 * __cosf(tv * T);
        wi[j] = e1 * __sinf(tv * T);
        qd[j] = qds[d];
        gx[j] = gxs[d];
    }
    for (int i = 0; i < 32; ++i) {
        float fa = 0.f, ka = 0.f;
        #pragma unroll
        for (int j = 0; j < 8; ++j) {
            fa = fmaf(qd[j], pr[j], fa);
            ka = fmaf(gx[j], pr[j], ka);
            float nr = fmaf(pr[j], wr[j], -(pi[j] * wi[j]));
            float ni = fmaf(pr[j], wi[j],  (pi[j] * wr[j]));
            pr[j] = nr; pi[j] = ni;
        }
        fa += __shfl_xor(fa, 1); fa += __shfl_xor(fa, 2);
        ka += __shfl_xor(ka, 1); ka += __shfl_xor(ka, 2);
        if (q4 == 0) {
            float fv = 2.0f * T * fa;
            fk_all[i * 64 + lc] = pack_bf16x2(fv, ka);   // banks = lc&31: conflict-free
            if (lc == 0) f_lds[i] = fv;
        }
    }
    __syncthreads();
    // coalesced FKf store: thread t -> l = t*8..t*8+7
    {
        unsigned v[8];
        #pragma unroll
        for (int j = 0; j < 8; ++j) {
            int l = t * 8 + j;
            v[j] = fk_all[(l & 31) * 64 + (l >> 5)];
        }
        uint4* dst = (uint4*)(FKf + (size_t)h * L_ + t * 8);
        dst[0] = make_uint4(v[0], v[1], v[2], v[3]);
        dst[1] = make_uint4(v[4], v[5], v[6], v[7]);
    }
    // phase 2: operand matrices (fp16)
    for (int e = t; e < 64 * 32; e += 256) {
        int m = e >> 5, i = e & 31;
        int d = m & 31;
        float av = avs[d], tv = tvs[d];
        float z  = T * (float)(31 - i);
        float ex = __expf(av * z);
        float v  = (m < 32) ? ex * __cosf(tv * z) : ex * __sinf(tv * z);
        AB[(size_t)h * 2048 + e] = (_Float16)v;
    }
    for (int e = t; e < 32 * 96; e += 256) {
        int i = e / 96, k = e - i * 96;
        float v = 0.f;
        if (k < 32) {
            if (k <= i) v = f_lds[i - k];
        } else {
            int d = (k < 64) ? k - 32 : k - 64;
            float av = avs[d], tv = tvs[d];
            float qs = 2.0f * T * qds[d];
            float z  = T * (float)(i + 1);
            float ex = __expf(av * z);
            v = (k < 64) ? qs * ex * __cosf(tv * z) : -qs * ex * __sinf(tv * z);
        }
        CB[(size_t)h * 3072 + e] = (_Float16)v;
    }
}

// ---------------- scan_mfma (R4-proven, untouched): 2 waves per (b,h) ----------------
__global__ __launch_bounds__(128, 6) void scan_mfma_kernel(
        const float* __restrict__ u, const _Float16* __restrict__ AB,
        const _Float16* __restrict__ CB, const unsigned* __restrict__ WPh,
        const float* __restrict__ Dp, const unsigned* __restrict__ FKf,
        __hip_bfloat16* __restrict__ y) {
    __shared__ __align__(16) unsigned El[64 * EP];
    int wid = threadIdx.x >> 6, lane = threadIdx.x & 63;
    int h = blockIdx.x, b = blockIdx.y;
    int ln = lane & 15, qq = lane >> 4;
    const float* ug = u + (size_t)(b * H_ + h) * L_;

    // ---- U fragments (fp16), all 4 column-tiles (needed as M1 B-operand) ----
    half8 uf[4];
    #pragma unroll
    for (int nb = 0; nb < 4; ++nb) {
        const float* p = ug + (nb * 16 + ln) * 32 + qq * 8;
        float4 a0 = *(const float4*)p;
        float4 a1 = *(const float4*)(p + 4);
        unsigned* vp = (unsigned*)&uf[nb];
        vp[0] = pack_f16x2(a0.x, a0.y);
        vp[1] = pack_f16x2(a0.z, a0.w);
        vp[2] = pack_f16x2(a1.x, a1.y);
        vp[3] = pack_f16x2(a1.z, a1.w);
    }

    // ---- M1: this wave's Er/Ei rows (d-half) ----
    const _Float16* ABh = AB + (size_t)h * 2048;
    int j0 = wid * 8 + qq * 2;
    #pragma unroll
    for (int e = 0; e < 2; ++e) {       // e=0: Re rows, e=1: Im rows
        half8 af = *(const half8*)&ABh[(e * 32 + wid * 16 + ln) * 32 + qq * 8];
        #pragma unroll
        for (int nb = 0; nb < 4; ++nb) {
            float4v acc = (float4v){0.f, 0.f, 0.f, 0.f};
            acc = __builtin_amdgcn_mfma_f32_16x16x32_f16(af, uf[nb], acc, 0, 0, 0);
            unsigned p0 = pack_f16x2(acc[0], acc[1]);
            unsigned p1 = pack_f16x2(acc[2], acc[3]);
            *(uint2*)&El[(nb * 16 + ln) * EP + e * 16 + j0] = make_uint2(p0, p1);
        }
    }
    // own-wave write->read: DS ops drain, no cross-wave dependency yet
    asm volatile("s_waitcnt lgkmcnt(0)" ::: "memory");
    __builtin_amdgcn_sched_barrier(0);

    // ---- packed-fp16 scan over chunks (lane = c), own 8 pairs ----
    int c = lane;
    unsigned sr[8], si[8];
    {
        const unsigned* rp = &El[c * EP + wid * 8];
        uint4 r0 = *(const uint4*)rp;
        uint4 r1 = *(const uint4*)(rp + 4);
        uint4 i0 = *(const uint4*)(rp + 16);
        uint4 i1 = *(const uint4*)(rp + 20);
        sr[0]=r0.x; sr[1]=r0.y; sr[2]=r0.z; sr[3]=r0.w;
        sr[4]=r1.x; sr[5]=r1.y; sr[6]=r1.z; sr[7]=r1.w;
        si[0]=i0.x; si[1]=i0.y; si[2]=i0.z; si[3]=i0.w;
        si[4]=i1.x; si[5]=i1.y; si[6]=i1.z; si[7]=i1.w;
    }
    const unsigned* mpb = WPh + (size_t)h * 6 * 32;
    #pragma unroll
    for (int st = 0; st < 6; ++st) {
        int off = 1 << st;
        int src = (c - off) & 63;
        bool act = c >= off;
        const unsigned* mp = mpb + st * 32 + wid * 8;
        #pragma unroll
        for (int jj = 0; jj < 8; ++jj) {
            unsigned prp = (unsigned)__shfl((int)sr[jj], src);
            unsigned pip = (unsigned)__shfl((int)si[jj], src);
            if (!act) { prp = 0u; pip = 0u; }
            unsigned mru = mp[jj];
            unsigned miu = mp[16 + jj];
            unsigned min_ = miu ^ 0x80008000u;          // -Mi via sign flip
            half2v pr = *(half2v*)&prp, pi = *(half2v*)&pip;
            half2v Mr = *(half2v*)&mru, Mi = *(half2v*)&miu, Mni = *(half2v*)&min_;
            half2v s_r = *(half2v*)&sr[jj], s_i = *(half2v*)&si[jj];
            half2v nr = pk_fma16(pr, Mr, pk_fma16(pi, Mni, s_r));
            half2v ni = pk_fma16(pr, Mi, pk_fma16(pi, Mr,  s_i));
            sr[jj] = *(unsigned*)&nr; si[jj] = *(unsigned*)&ni;
        }
    }
    {   // exclusive shift: carry entering chunk c = S_{c-1}; lane 0 -> 0
        int srcm1 = (c - 1) & 63;
        #pragma unroll
        for (int jj = 0; jj < 8; ++jj) {
            unsigned a0 = (unsigned)__shfl((int)sr[jj], srcm1);
            unsigned b0 = (unsigned)__shfl((int)si[jj], srcm1);
            if (c == 0) { a0 = 0u; b0 = 0u; }
            sr[jj] = a0; si[jj] = b0;
        }
    }
    {   // carries back to same El slots
        unsigned* wp = &El[c * EP + wid * 8];
        *(uint4*)wp        = make_uint4(sr[0], sr[1], sr[2], sr[3]);
        *(uint4*)(wp + 4)  = make_uint4(sr[4], sr[5], sr[6], sr[7]);
        *(uint4*)(wp + 16) = make_uint4(si[0], si[1], si[2], si[3]);
        *(uint4*)(wp + 20) = make_uint4(si[4], si[5], si[6], si[7]);
    }
    // prefetch FK for epilogue; latency hides under barrier + M2
    const unsigned* fgh = FKf + (size_t)h * L_;
    uint4 fkp[2][2];
    #pragma unroll
    for (int nbi = 0; nbi < 2; ++nbi) {
        int col = (2 * wid + nbi) * 16 + ln;
        fkp[nbi][0] = *(const uint4*)&fgh[col * 32 + qq * 4];
        fkp[nbi][1] = *(const uint4*)&fgh[col * 32 + 16 + qq * 4];
    }
    __syncthreads();

    // ---- M2: y_pre = [T_f | Qr | -Qi] @ [U; Sr; Si], this wave's 2 col-tiles ----
    const _Float16* CBh = CB + (size_t)h * 3072;
    float4v acc2[2][2];
    #pragma unroll
    for (int mb = 0; mb < 2; ++mb)
        #pragma unroll
        for (int nbi = 0; nbi < 2; ++nbi)
            acc2[mb][nbi] = (float4v){0.f, 0.f, 0.f, 0.f};
    #pragma unroll
    for (int ks = 0; ks < 3; ++ks) {
        half8 a2[2];
        a2[0] = *(const half8*)&CBh[(ln)      * 96 + ks * 32 + qq * 8];
        a2[1] = *(const half8*)&CBh[(16 + ln) * 96 + ks * 32 + qq * 8];
        #pragma unroll
        for (int nbi = 0; nbi < 2; ++nbi) {
            int col = (2 * wid + nbi) * 16 + ln;
            half8 bfv;
            if (ks == 0) bfv = uf[2 * wid + nbi];
            else {
                int off = (ks == 1) ? 0 : 16;
                bfv = *(const half8*)&El[col * EP + off + qq * 4];
            }
            acc2[0][nbi] = __builtin_amdgcn_mfma_f32_16x16x32_f16(a2[0], bfv, acc2[0][nbi], 0, 0, 0);
            acc2[1][nbi] = __builtin_amdgcn_mfma_f32_16x16x32_f16(a2[1], bfv, acc2[1][nbi], 0, 0, 0);
        }
    }

    // ---- epilogue: y = y_pre + c0*u + c1*f + k0, fast gelu, pack bf16 ----
    float f0; { f0 = unpack_bf16x2(fgh[0]).x; }
    float c0v = Dp[h] - 0.5f * f0;
    float c1v = -0.5f * ug[0];
    #pragma unroll
    for (int nbi = 0; nbi < 2; ++nbi) {
        int col = (2 * wid + nbi) * 16 + ln;
        #pragma unroll
        for (int mb = 0; mb < 2; ++mb) {
            int l0 = col * 32 + mb * 16 + qq * 4;
            float4 u4 = *(const float4*)(ug + l0);
            uint4 fkv = fkp[nbi][mb];
            float us[4] = {u4.x, u4.y, u4.z, u4.w};
            unsigned fs[4] = {fkv.x, fkv.y, fkv.z, fkv.w};
            float g[4];
            #pragma unroll
            for (int r = 0; r < 4; ++r) {
                float2 fk = unpack_bf16x2(fs[r]);
                float yv = acc2[mb][nbi][r] + fmaf(c0v, us[r], fmaf(c1v, fk.x, fk.y));
                g[r] = gelu_fast(yv);
            }
            uint2 yo;
            yo.x = pack_bf16x2(g[0], g[1]);
            yo.y = pack_bf16x2(g[2], g[3]);
            *(uint2*)((short*)y + (size_t)(b * H_ + h) * L_ + l0) = yo;
        }
    }
}

// ---------------- gemm v2: fused transpose + double-buffered pipeline ----------------
// R7's fused staging put the ~500cy global load on every K-step's critical path
// (load -> pack -> ds_write -> barrier -> MFMA, serialized x16). Now: issue
// kt+1's loads (A via global_load_lds to buf^1, B via 2 reg loads) BEFORE
// computing kt's MFMAs; pack+ds_write of kt+1 lands after the MFMA cluster
// (sched_barrier-pinned), then ONE barrier per step. Load latency hides under
// the MFMA+frag-read work. Math/layouts byte-identical to R7 (verified).
__global__ __launch_bounds__(256) void gemm_kernel(
        const __hip_bfloat16* __restrict__ Wb, const __hip_bfloat16* __restrict__ y,
        const float* __restrict__ bias, float* __restrict__ out) {
    __shared__ __align__(16) short    As[2][64 * 32];
    __shared__ __align__(16) unsigned Bs[2][128 * 16];
    int h0 = blockIdx.x * 64;
    int l0 = blockIdx.y * 128;
    int b  = blockIdx.z;
    int t    = threadIdx.x;
    int lane = t & 63, wave = t >> 6;
    int m_off = (wave >> 1) * 32, n_off = (wave & 1) * 64;
    int quad = lane >> 4, ln = lane & 15;

    float4v acc[2][4];
    #pragma unroll
    for (int mt = 0; mt < 2; ++mt)
        #pragma unroll
        for (int nt = 0; nt < 4; ++nt)
            acc[mt][nt] = (float4v){0.f, 0.f, 0.f, 0.f};

    const short* Wg = (const short*)Wb;
    const short* Yg = (const short*)y + (size_t)b * 512 * L_;   // [f][l]

    int r  = t >> 2;       // 0..63 (A staging)
    int qd = t & 3;
    int fp = t & 15;       // B staging: f-pair 0..15
    int n8 = t >> 4;       // B staging: l-octet 0..15
    const short* ybase = Yg + (size_t)(2 * fp) * L_ + l0 + n8 * 8;

    // prologue: stage kt=0 into buffer 0
    load_lds16(Wg + (h0 + r) * 512 + qd * 8, &As[0][t * 8]);
    {
        uint4 ya = *(const uint4*)ybase;
        uint4 yb = *(const uint4*)(ybase + L_);
        unsigned au[4] = {ya.x, ya.y, ya.z, ya.w};
        unsigned bu[4] = {yb.x, yb.y, yb.z, yb.w};
        #pragma unroll
        for (int i2 = 0; i2 < 4; ++i2) {
            int na = n8 * 8 + 2 * i2, nb = na + 1;
            Bs[0][na * 16 + (fp ^ (((na >> 2) & 3) << 2))] = (au[i2] & 0xFFFFu) | (bu[i2] << 16);
            Bs[0][nb * 16 + (fp ^ (((nb >> 2) & 3) << 2))] = (au[i2] >> 16) | (bu[i2] & 0xFFFF0000u);
        }
    }
    __syncthreads();

    for (int kt = 0; kt < 15; ++kt) {
        int cur = kt & 1, nxt = cur ^ 1;
        int k1 = (kt + 1) * 32;
        // issue next-step loads FIRST (latency overlaps this step's compute)
        load_lds16(Wg + (h0 + r) * 512 + k1 + qd * 8, &As[nxt][t * 8]);
        uint4 za = *(const uint4*)(ybase + (size_t)k1 * L_);
        uint4 zb = *(const uint4*)(ybase + (size_t)(k1 + 1) * L_);

        short8 af[2], bf[4];
        #pragma unroll
        for (int mt = 0; mt < 2; ++mt)
            af[mt] = *(const short8*)&As[cur][(m_off + mt * 16 + ln) * 32 + quad * 8];
        #pragma unroll
        for (int nt = 0; nt < 4; ++nt) {
            int n = n_off + nt * 16 + ln;
            bf[nt] = *(const short8*)&Bs[cur][n * 16 + ((quad * 4) ^ (((n >> 2) & 3) << 2))];
        }
        #pragma unroll
        for (int mt = 0; mt < 2; ++mt)
            #pragma unroll
            for (int nt = 0; nt < 4; ++nt)
                acc[mt][nt] = __builtin_amdgcn_mfma_f32_16x16x32_bf16(
                    af[mt], bf[nt], acc[mt][nt], 0, 0, 0);
        __builtin_amdgcn_sched_barrier(0);   // keep B-write below the MFMA cluster

        {
            unsigned au[4] = {za.x, za.y, za.z, za.w};
            unsigned bu[4] = {zb.x, zb.y, zb.z, zb.w};
            #pragma unroll
            for (int i2 = 0; i2 < 4; ++i2) {
                int na = n8 * 8 + 2 * i2, nb = na + 1;
                Bs[nxt][na * 16 + (fp ^ (((na >> 2) & 3) << 2))] = (au[i2] & 0xFFFFu) | (bu[i2] << 16);
                Bs[nxt][nb * 16 + (fp ^ (((nb >> 2) & 3) << 2))] = (au[i2] >> 16) | (bu[i2] & 0xFFFF0000u);
            }
        }
        __syncthreads();
    }
    {   // tail: kt = 15, buffer 1, compute only
        short8 af[2], bf[4];
        #pragma unroll
        for (int mt = 0; mt < 2; ++mt)
            af[mt] = *(const short8*)&As[1][(m_off + mt * 16 + ln) * 32 + quad * 8];
        #pragma unroll
        for (int nt = 0; nt < 4; ++nt) {
            int n = n_off + nt * 16 + ln;
            bf[nt] = *(const short8*)&Bs[1][n * 16 + ((quad * 4) ^ (((n >> 2) & 3) << 2))];
        }
        #pragma unroll
        for (int mt = 0; mt < 2; ++mt)
            #pragma unroll
            for (int nt = 0; nt < 4; ++nt)
                acc[mt][nt] = __builtin_amdgcn_mfma_f32_16x16x32_bf16(
                    af[mt], bf[nt], acc[mt][nt], 0, 0, 0);
    }

    #pragma unroll
    for (int mt = 0; mt < 2; ++mt) {
        #pragma unroll
        for (int nt = 0; nt < 4; ++nt) {
            int hh = h0 + m_off + mt * 16 + quad * 4;
            int ll = l0 + n_off + nt * 16 + ln;
            #pragma unroll
            for (int r2 = 0; r2 < 4; ++r2)
                out[((size_t)(b * H_ + hh + r2)) * L_ + ll] = acc[mt][nt][r2] + bias[hh + r2];
        }
    }
}

extern "C" void kernel_launch(void* const* d_in, const int* in_sizes, int n_in,
                              void* d_out, int out_size, void* d_ws, size_t ws_size,
                              hipStream_t stream) {
    const float* u    = (const float*)d_in[0];
    const float* a    = (const float*)d_in[1];
    const float* th   = (const float*)d_in[2];
    const float* bb   = (const float*)d_in[3];
    const float* cc   = (const float*)d_in[4];
    const float* x0   = (const float*)d_in[5];
    const float* Dp   = (const float*)d_in[6];
    const float* W    = (const float*)d_in[7];
    const float* bias = (const float*)d_in[8];
    float* out = (float*)d_out;
    char* ws = (char*)d_ws;

    // layout: FKf 4M @0 | y 16M @20M | Wb 0.5M @36M | AB 2M @37M |
    //         CB 3M @39M | WPh fp16 384KB @42M
    unsigned*       FKf = (unsigned*)ws;
    __hip_bfloat16* y   = (__hip_bfloat16*)(ws + (20ull << 20));
    __hip_bfloat16* Wb  = (__hip_bfloat16*)(ws + (36ull << 20));
    _Float16*       AB  = (_Float16*)(ws + (37ull << 20));
    _Float16*       CB  = (_Float16*)(ws + (39ull << 20));
    _Float16*       WPh = (_Float16*)(ws + (42ull << 20));

    hipLaunchKernelGGL(fkprep_kernel,     dim3(H_),        dim3(256), 0, stream,
                       a, th, bb, cc, x0, W, Wb, FKf, AB, CB, WPh);
    hipLaunchKernelGGL(scan_mfma_kernel,  dim3(H_, B_),    dim3(128), 0, stream,
                       u, AB, CB, (const unsigned*)WPh, Dp, FKf, y);
    hipLaunchKernelGGL(gemm_kernel,       dim3(8, 16, 8),  dim3(256), 0, stream,
                       Wb, y, bias, out);
}

// Round 9
// 162.808 us; speedup vs baseline: 1.1944x; 1.0058x over previous
//
#include <hip/hip_runtime.h>
#include <hip/hip_bf16.h>

#define B_  8
#define H_  512
#define L_  2048
#define D2_ 32
#define NC_ 64
#define LC_ 32    // L_/NC_
#define EP  36    // E_lds row pitch in u32 (16B-aligned rows)

typedef __attribute__((ext_vector_type(8))) short short8;     // 8 bf16 (4 VGPRs)
typedef __attribute__((ext_vector_type(8))) _Float16 half8;   // 8 fp16 (4 VGPRs)
typedef __attribute__((ext_vector_type(2))) _Float16 half2v;  // packed fp16 (v_pk_*)
typedef __attribute__((ext_vector_type(4))) float float4v;    // 4 fp32 acc

__device__ __forceinline__ half2v pk_fma16(half2v a, half2v b, half2v c) {
    return __builtin_elementwise_fma(a, b, c);
}

// tanh-form GELU: max |err| vs exact ~3e-4, far below bf16 y-storage ulp.
__device__ __forceinline__ float gelu_fast(float x) {
    float q = x * fmaf(0.044715f, x * x, 1.0f);
    float s = __expf(-1.5957691216057308f * q);   // e^{-2*0.79788456*q}
    return __fdividef(x, 1.0f + s);               // x * sigmoid(2w)
}

__device__ __forceinline__ unsigned pack_bf16x2(float x, float y) {
    __hip_bfloat162 p = __float22bfloat162_rn(make_float2(x, y));
    return *(unsigned*)&p;
}
__device__ __forceinline__ float2 unpack_bf16x2(unsigned v) {
    __hip_bfloat162 p = *(__hip_bfloat162*)&v;
    return __bfloat1622float2(p);
}
__device__ __forceinline__ unsigned pack_f16x2(float x, float y) {
    auto v = __builtin_amdgcn_cvt_pkrtz(x, y);    // v_cvt_pkrtz_f16_f32
    return *(unsigned*)&v;
}

__device__ __forceinline__ void load_lds16(const void* g, void* l) {
    __builtin_amdgcn_global_load_lds((const __attribute__((address_space(1))) unsigned int*)g,
                                     (__attribute__((address_space(3))) unsigned int*)l, 16, 0, 0);
}

// ---------------- fkprep: params + fk (f,k0) + MFMA operands + W-cast, 1 block/h ----
__global__ __launch_bounds__(256) void fkprep_kernel(
        const float* __restrict__ a, const float* __restrict__ th,
        const float* __restrict__ bb, const float* __restrict__ cc,
        const float* __restrict__ x0, const float* __restrict__ W,
        __hip_bfloat16* __restrict__ Wb, unsigned* __restrict__ FKf,
        _Float16* __restrict__ AB, _Float16* __restrict__ CB,
        _Float16* __restrict__ WPh) {
    __shared__ float avs[32], tvs[32], qds[32], gxs[32], f_lds[32];
    __shared__ unsigned fk_all[32 * 64];     // [i][lc]
    int h = blockIdx.x;
    int t = threadIdx.x;
    const float T = 1.0f / (float)(L_ - 1);
    // W row cast (independent of everything else)
    Wb[(size_t)h * 512 + t]       = __float2bfloat16(W[(size_t)h * 512 + t]);
    Wb[(size_t)h * 512 + t + 256] = __float2bfloat16(W[(size_t)h * 512 + t + 256]);
    // phase 0: per-d params + WPh
    if (t < 32) {
        int d = t;
        float av = -fabsf(a[h * D2_ + d]);
        float tv = th[h * D2_ + d];
        avs[d] = av; tvs[d] = tv;
        qds[d] = bb[h * D2_ + d] * cc[h * D2_ + d];
        gxs[d] = 2.0f * cc[h * D2_ + d] * x0[h * D2_ + d];
        #pragma unroll
        for (int k = 0; k < 6; ++k) {
            float len = (float)(32 << k);        // 32 * 2^k steps
            float e2  = __expf(av * T * len);
            float an  = tv * T * len;
            WPh[((size_t)h * 6 + k) * 64 + d]      = (_Float16)(e2 * __cosf(an));
            WPh[((size_t)h * 6 + k) * 64 + 32 + d] = (_Float16)(e2 * __sinf(an));
        }
    }
    __syncthreads();
    // phase 1: fk recurrence
    int q4 = t & 3, lc = t >> 2;
    float z0 = T * (float)(lc * 32);
    float pr[8], pi[8], wr[8], wi[8], qd[8], gx[8];
    #pragma unroll
    for (int j = 0; j < 8; ++j) {
        int d = q4 * 8 + j;
        float aa = avs[d], tv = tvs[d];
        float e0 = __expf(aa * z0);
        pr[j] = e0 * __cosf(tv * z0);
        pi[j] = e0 * __sinf(tv * z0);
        float e1 = __expf(aa * T);
        wr[j] = e1 * __cosf(tv * T);
        wi[j] = e1 * __sinf(tv * T);
        qd[j] = qds[d];
        gx[j] = gxs[d];
    }
    for (int i = 0; i < 32; ++i) {
        float fa = 0.f, ka = 0.f;
        #pragma unroll
        for (int j = 0; j < 8; ++j) {
            fa = fmaf(qd[j], pr[j], fa);
            ka = fmaf(gx[j], pr[j], ka);
            float nr = fmaf(pr[j], wr[j], -(pi[j] * wi[j]));
            float ni = fmaf(pr[j], wi[j],  (pi[j] * wr[j]));
            pr[j] = nr; pi[j] = ni;
        }
        fa += __shfl_xor(fa, 1); fa += __shfl_xor(fa, 2);
        ka += __shfl_xor(ka, 1); ka += __shfl_xor(ka, 2);
        if (q4 == 0) {
            float fv = 2.0f * T * fa;
            fk_all[i * 64 + lc] = pack_bf16x2(fv, ka);   // banks = lc&31: conflict-free
            if (lc == 0) f_lds[i] = fv;
        }
    }
    __syncthreads();
    // coalesced FKf store: thread t -> l = t*8..t*8+7
    {
        unsigned v[8];
        #pragma unroll
        for (int j = 0; j < 8; ++j) {
            int l = t * 8 + j;
            v[j] = fk_all[(l & 31) * 64 + (l >> 5)];
        }
        uint4* dst = (uint4*)(FKf + (size_t)h * L_ + t * 8);
        dst[0] = make_uint4(v[0], v[1], v[2], v[3]);
        dst[1] = make_uint4(v[4], v[5], v[6], v[7]);
    }
    // phase 2: operand matrices (fp16)
    for (int e = t; e < 64 * 32; e += 256) {
        int m = e >> 5, i = e & 31;
        int d = m & 31;
        float av = avs[d], tv = tvs[d];
        float z  = T * (float)(31 - i);
        float ex = __expf(av * z);
        float v  = (m < 32) ? ex * __cosf(tv * z) : ex * __sinf(tv * z);
        AB[(size_t)h * 2048 + e] = (_Float16)v;
    }
    for (int e = t; e < 32 * 96; e += 256) {
        int i = e / 96, k = e - i * 96;
        float v = 0.f;
        if (k < 32) {
            if (k <= i) v = f_lds[i - k];
        } else {
            int d = (k < 64) ? k - 32 : k - 64;
            float av = avs[d], tv = tvs[d];
            float qs = 2.0f * T * qds[d];
            float z  = T * (float)(i + 1);
            float ex = __expf(av * z);
            v = (k < 64) ? qs * ex * __cosf(tv * z) : -qs * ex * __sinf(tv * z);
        }
        CB[(size_t)h * 3072 + e] = (_Float16)v;
    }
}

// ---------------- scan_mfma (R4-proven, untouched): 2 waves per (b,h) ----------------
// Grid (h, b): flat id = h + 512*b -> XCD = h%8, so all 8 b-blocks of an h share
// one XCD's L2 for AB/CB/FKf/WPh (~18KB/h, 64 h's fit in 4MB) — already optimal.
__global__ __launch_bounds__(128, 6) void scan_mfma_kernel(
        const float* __restrict__ u, const _Float16* __restrict__ AB,
        const _Float16* __restrict__ CB, const unsigned* __restrict__ WPh,
        const float* __restrict__ Dp, const unsigned* __restrict__ FKf,
        __hip_bfloat16* __restrict__ y) {
    __shared__ __align__(16) unsigned El[64 * EP];
    int wid = threadIdx.x >> 6, lane = threadIdx.x & 63;
    int h = blockIdx.x, b = blockIdx.y;
    int ln = lane & 15, qq = lane >> 4;
    const float* ug = u + (size_t)(b * H_ + h) * L_;

    // ---- U fragments (fp16), all 4 column-tiles (needed as M1 B-operand) ----
    half8 uf[4];
    #pragma unroll
    for (int nb = 0; nb < 4; ++nb) {
        const float* p = ug + (nb * 16 + ln) * 32 + qq * 8;
        float4 a0 = *(const float4*)p;
        float4 a1 = *(const float4*)(p + 4);
        unsigned* vp = (unsigned*)&uf[nb];
        vp[0] = pack_f16x2(a0.x, a0.y);
        vp[1] = pack_f16x2(a0.z, a0.w);
        vp[2] = pack_f16x2(a1.x, a1.y);
        vp[3] = pack_f16x2(a1.z, a1.w);
    }

    // ---- M1: this wave's Er/Ei rows (d-half) ----
    const _Float16* ABh = AB + (size_t)h * 2048;
    int j0 = wid * 8 + qq * 2;
    #pragma unroll
    for (int e = 0; e < 2; ++e) {       // e=0: Re rows, e=1: Im rows
        half8 af = *(const half8*)&ABh[(e * 32 + wid * 16 + ln) * 32 + qq * 8];
        #pragma unroll
        for (int nb = 0; nb < 4; ++nb) {
            float4v acc = (float4v){0.f, 0.f, 0.f, 0.f};
            acc = __builtin_amdgcn_mfma_f32_16x16x32_f16(af, uf[nb], acc, 0, 0, 0);
            unsigned p0 = pack_f16x2(acc[0], acc[1]);
            unsigned p1 = pack_f16x2(acc[2], acc[3]);
            *(uint2*)&El[(nb * 16 + ln) * EP + e * 16 + j0] = make_uint2(p0, p1);
        }
    }
    // own-wave write->read: DS ops drain, no cross-wave dependency yet
    asm volatile("s_waitcnt lgkmcnt(0)" ::: "memory");
    __builtin_amdgcn_sched_barrier(0);

    // ---- packed-fp16 scan over chunks (lane = c), own 8 pairs ----
    int c = lane;
    unsigned sr[8], si[8];
    {
        const unsigned* rp = &El[c * EP + wid * 8];
        uint4 r0 = *(const uint4*)rp;
        uint4 r1 = *(const uint4*)(rp + 4);
        uint4 i0 = *(const uint4*)(rp + 16);
        uint4 i1 = *(const uint4*)(rp + 20);
        sr[0]=r0.x; sr[1]=r0.y; sr[2]=r0.z; sr[3]=r0.w;
        sr[4]=r1.x; sr[5]=r1.y; sr[6]=r1.z; sr[7]=r1.w;
        si[0]=i0.x; si[1]=i0.y; si[2]=i0.z; si[3]=i0.w;
        si[4]=i1.x; si[5]=i1.y; si[6]=i1.z; si[7]=i1.w;
    }
    const unsigned* mpb = WPh + (size_t)h * 6 * 32;
    #pragma unroll
    for (int st = 0; st < 6; ++st) {
        int off = 1 << st;
        int src = (c - off) & 63;
        bool act = c >= off;
        const unsigned* mp = mpb + st * 32 + wid * 8;
        #pragma unroll
        for (int jj = 0; jj < 8; ++jj) {
            unsigned prp = (unsigned)__shfl((int)sr[jj], src);
            unsigned pip = (unsigned)__shfl((int)si[jj], src);
            if (!act) { prp = 0u; pip = 0u; }
            unsigned mru = mp[jj];
            unsigned miu = mp[16 + jj];
            unsigned min_ = miu ^ 0x80008000u;          // -Mi via sign flip
            half2v pr = *(half2v*)&prp, pi = *(half2v*)&pip;
            half2v Mr = *(half2v*)&mru, Mi = *(half2v*)&miu, Mni = *(half2v*)&min_;
            half2v s_r = *(half2v*)&sr[jj], s_i = *(half2v*)&si[jj];
            half2v nr = pk_fma16(pr, Mr, pk_fma16(pi, Mni, s_r));
            half2v ni = pk_fma16(pr, Mi, pk_fma16(pi, Mr,  s_i));
            sr[jj] = *(unsigned*)&nr; si[jj] = *(unsigned*)&ni;
        }
    }
    {   // exclusive shift: carry entering chunk c = S_{c-1}; lane 0 -> 0
        int srcm1 = (c - 1) & 63;
        #pragma unroll
        for (int jj = 0; jj < 8; ++jj) {
            unsigned a0 = (unsigned)__shfl((int)sr[jj], srcm1);
            unsigned b0 = (unsigned)__shfl((int)si[jj], srcm1);
            if (c == 0) { a0 = 0u; b0 = 0u; }
            sr[jj] = a0; si[jj] = b0;
        }
    }
    {   // carries back to same El slots
        unsigned* wp = &El[c * EP + wid * 8];
        *(uint4*)wp        = make_uint4(sr[0], sr[1], sr[2], sr[3]);
        *(uint4*)(wp + 4)  = make_uint4(sr[4], sr[5], sr[6], sr[7]);
        *(uint4*)(wp + 16) = make_uint4(si[0], si[1], si[2], si[3]);
        *(uint4*)(wp + 20) = make_uint4(si[4], si[5], si[6], si[7]);
    }
    // prefetch FK for epilogue; latency hides under barrier + M2
    const unsigned* fgh = FKf + (size_t)h * L_;
    uint4 fkp[2][2];
    #pragma unroll
    for (int nbi = 0; nbi < 2; ++nbi) {
        int col = (2 * wid + nbi) * 16 + ln;
        fkp[nbi][0] = *(const uint4*)&fgh[col * 32 + qq * 4];
        fkp[nbi][1] = *(const uint4*)&fgh[col * 32 + 16 + qq * 4];
    }
    __syncthreads();

    // ---- M2: y_pre = [T_f | Qr | -Qi] @ [U; Sr; Si], this wave's 2 col-tiles ----
    const _Float16* CBh = CB + (size_t)h * 3072;
    float4v acc2[2][2];
    #pragma unroll
    for (int mb = 0; mb < 2; ++mb)
        #pragma unroll
        for (int nbi = 0; nbi < 2; ++nbi)
            acc2[mb][nbi] = (float4v){0.f, 0.f, 0.f, 0.f};
    #pragma unroll
    for (int ks = 0; ks < 3; ++ks) {
        half8 a2[2];
        a2[0] = *(const half8*)&CBh[(ln)      * 96 + ks * 32 + qq * 8];
        a2[1] = *(const half8*)&CBh[(16 + ln) * 96 + ks * 32 + qq * 8];
        #pragma unroll
        for (int nbi = 0; nbi < 2; ++nbi) {
            int col = (2 * wid + nbi) * 16 + ln;
            half8 bfv;
            if (ks == 0) bfv = uf[2 * wid + nbi];
            else {
                int off = (ks == 1) ? 0 : 16;
                bfv = *(const half8*)&El[col * EP + off + qq * 4];
            }
            acc2[0][nbi] = __builtin_amdgcn_mfma_f32_16x16x32_f16(a2[0], bfv, acc2[0][nbi], 0, 0, 0);
            acc2[1][nbi] = __builtin_amdgcn_mfma_f32_16x16x32_f16(a2[1], bfv, acc2[1][nbi], 0, 0, 0);
        }
    }

    // ---- epilogue: y = y_pre + c0*u + c1*f + k0, fast gelu, pack bf16 ----
    float f0; { f0 = unpack_bf16x2(fgh[0]).x; }
    float c0v = Dp[h] - 0.5f * f0;
    float c1v = -0.5f * ug[0];
    #pragma unroll
    for (int nbi = 0; nbi < 2; ++nbi) {
        int col = (2 * wid + nbi) * 16 + ln;
        #pragma unroll
        for (int mb = 0; mb < 2; ++mb) {
            int l0 = col * 32 + mb * 16 + qq * 4;
            float4 u4 = *(const float4*)(ug + l0);
            uint4 fkv = fkp[nbi][mb];
            float us[4] = {u4.x, u4.y, u4.z, u4.w};
            unsigned fs[4] = {fkv.x, fkv.y, fkv.z, fkv.w};
            float g[4];
            #pragma unroll
            for (int r = 0; r < 4; ++r) {
                float2 fk = unpack_bf16x2(fs[r]);
                float yv = acc2[mb][nbi][r] + fmaf(c0v, us[r], fmaf(c1v, fk.x, fk.y));
                g[r] = gelu_fast(yv);
            }
            uint2 yo;
            yo.x = pack_bf16x2(g[0], g[1]);
            yo.y = pack_bf16x2(g[2], g[3]);
            *(uint2*)((short*)y + (size_t)(b * H_ + h) * L_ + l0) = yo;
        }
    }
}

// ---------------- gemm v3: double-buffered pipeline + XCD-correct grid ----------------
// Grid swapped to (x=l-tile, y=h-tile): flat id = x + 16y + 128z -> XCD = id%8 =
// x%8, so all 8 h-tile blocks sharing one 2MB y l-slice land on the SAME XCD's
// L2 (R7/R8's x=h-tile put them on 8 DIFFERENT XCDs: adjacent blockIdx
// round-robins across XCDs, so "adjacent dispatch" gave zero L2 sharing and
// each XCD re-pulled the slice from L3). W (0.5MB) coexists in L2.
__global__ __launch_bounds__(256) void gemm_kernel(
        const __hip_bfloat16* __restrict__ Wb, const __hip_bfloat16* __restrict__ y,
        const float* __restrict__ bias, float* __restrict__ out) {
    __shared__ __align__(16) short    As[2][64 * 32];
    __shared__ __align__(16) unsigned Bs[2][128 * 16];
    int l0 = blockIdx.x * 128;
    int h0 = blockIdx.y * 64;
    int b  = blockIdx.z;
    int t    = threadIdx.x;
    int lane = t & 63, wave = t >> 6;
    int m_off = (wave >> 1) * 32, n_off = (wave & 1) * 64;
    int quad = lane >> 4, ln = lane & 15;

    float4v acc[2][4];
    #pragma unroll
    for (int mt = 0; mt < 2; ++mt)
        #pragma unroll
        for (int nt = 0; nt < 4; ++nt)
            acc[mt][nt] = (float4v){0.f, 0.f, 0.f, 0.f};

    const short* Wg = (const short*)Wb;
    const short* Yg = (const short*)y + (size_t)b * 512 * L_;   // [f][l]

    int r  = t >> 2;       // 0..63 (A staging)
    int qd = t & 3;
    int fp = t & 15;       // B staging: f-pair 0..15
    int n8 = t >> 4;       // B staging: l-octet 0..15
    const short* ybase = Yg + (size_t)(2 * fp) * L_ + l0 + n8 * 8;

    // prologue: stage kt=0 into buffer 0
    load_lds16(Wg + (h0 + r) * 512 + qd * 8, &As[0][t * 8]);
    {
        uint4 ya = *(const uint4*)ybase;
        uint4 yb = *(const uint4*)(ybase + L_);
        unsigned au[4] = {ya.x, ya.y, ya.z, ya.w};
        unsigned bu[4] = {yb.x, yb.y, yb.z, yb.w};
        #pragma unroll
        for (int i2 = 0; i2 < 4; ++i2) {
            int na = n8 * 8 + 2 * i2, nb = na + 1;
            Bs[0][na * 16 + (fp ^ (((na >> 2) & 3) << 2))] = (au[i2] & 0xFFFFu) | (bu[i2] << 16);
            Bs[0][nb * 16 + (fp ^ (((nb >> 2) & 3) << 2))] = (au[i2] >> 16) | (bu[i2] & 0xFFFF0000u);
        }
    }
    __syncthreads();

    for (int kt = 0; kt < 15; ++kt) {
        int cur = kt & 1, nxt = cur ^ 1;
        int k1 = (kt + 1) * 32;
        // issue next-step loads FIRST (latency overlaps this step's compute)
        load_lds16(Wg + (h0 + r) * 512 + k1 + qd * 8, &As[nxt][t * 8]);
        uint4 za = *(const uint4*)(ybase + (size_t)k1 * L_);
        uint4 zb = *(const uint4*)(ybase + (size_t)(k1 + 1) * L_);

        short8 af[2], bf[4];
        #pragma unroll
        for (int mt = 0; mt < 2; ++mt)
            af[mt] = *(const short8*)&As[cur][(m_off + mt * 16 + ln) * 32 + quad * 8];
        #pragma unroll
        for (int nt = 0; nt < 4; ++nt) {
            int n = n_off + nt * 16 + ln;
            bf[nt] = *(const short8*)&Bs[cur][n * 16 + ((quad * 4) ^ (((n >> 2) & 3) << 2))];
        }
        #pragma unroll
        for (int mt = 0; mt < 2; ++mt)
            #pragma unroll
            for (int nt = 0; nt < 4; ++nt)
                acc[mt][nt] = __builtin_amdgcn_mfma_f32_16x16x32_bf16(
                    af[mt], bf[nt], acc[mt][nt], 0, 0, 0);
        __builtin_amdgcn_sched_barrier(0);   // keep B-write below the MFMA cluster

        {
            unsigned au[4] = {za.x, za.y, za.z, za.w};
            unsigned bu[4] = {zb.x, zb.y, zb.z, zb.w};
            #pragma unroll
            for (int i2 = 0; i2 < 4; ++i2) {
                int na = n8 * 8 + 2 * i2, nb = na + 1;
                Bs[nxt][na * 16 + (fp ^ (((na >> 2) & 3) << 2))] = (au[i2] & 0xFFFFu) | (bu[i2] << 16);
                Bs[nxt][nb * 16 + (fp ^ (((nb >> 2) & 3) << 2))] = (au[i2] >> 16) | (bu[i2] & 0xFFFF0000u);
            }
        }
        __syncthreads();
    }
    {   // tail: kt = 15, buffer 1, compute only
        short8 af[2], bf[4];
        #pragma unroll
        for (int mt = 0; mt < 2; ++mt)
            af[mt] = *(const short8*)&As[1][(m_off + mt * 16 + ln) * 32 + quad * 8];
        #pragma unroll
        for (int nt = 0; nt < 4; ++nt) {
            int n = n_off + nt * 16 + ln;
            bf[nt] = *(const short8*)&Bs[1][n * 16 + ((quad * 4) ^ (((n >> 2) & 3) << 2))];
        }
        #pragma unroll
        for (int mt = 0; mt < 2; ++mt)
            #pragma unroll
            for (int nt = 0; nt < 4; ++nt)
                acc[mt][nt] = __builtin_amdgcn_mfma_f32_16x16x32_bf16(
                    af[mt], bf[nt], acc[mt][nt], 0, 0, 0);
    }

    #pragma unroll
    for (int mt = 0; mt < 2; ++mt) {
        #pragma unroll
        for (int nt = 0; nt < 4; ++nt) {
            int hh = h0 + m_off + mt * 16 + quad * 4;
            int ll = l0 + n_off + nt * 16 + ln;
            #pragma unroll
            for (int r2 = 0; r2 < 4; ++r2)
                out[((size_t)(b * H_ + hh + r2)) * L_ + ll] = acc[mt][nt][r2] + bias[hh + r2];
        }
    }
}

extern "C" void kernel_launch(void* const* d_in, const int* in_sizes, int n_in,
                              void* d_out, int out_size, void* d_ws, size_t ws_size,
                              hipStream_t stream) {
    const float* u    = (const float*)d_in[0];
    const float* a    = (const float*)d_in[1];
    const float* th   = (const float*)d_in[2];
    const float* bb   = (const float*)d_in[3];
    const float* cc   = (const float*)d_in[4];
    const float* x0   = (const float*)d_in[5];
    const float* Dp   = (const float*)d_in[6];
    const float* W    = (const float*)d_in[7];
    const float* bias = (const float*)d_in[8];
    float* out = (float*)d_out;
    char* ws = (char*)d_ws;

    // layout: FKf 4M @0 | y 16M @20M | Wb 0.5M @36M | AB 2M @37M |
    //         CB 3M @39M | WPh fp16 384KB @42M
    unsigned*       FKf = (unsigned*)ws;
    __hip_bfloat16* y   = (__hip_bfloat16*)(ws + (20ull << 20));
    __hip_bfloat16* Wb  = (__hip_bfloat16*)(ws + (36ull << 20));
    _Float16*       AB  = (_Float16*)(ws + (37ull << 20));
    _Float16*       CB  = (_Float16*)(ws + (39ull << 20));
    _Float16*       WPh = (_Float16*)(ws + (42ull << 20));

    hipLaunchKernelGGL(fkprep_kernel,     dim3(H_),        dim3(256), 0, stream,
                       a, th, bb, cc, x0, W, Wb, FKf, AB, CB, WPh);
    hipLaunchKernelGGL(scan_mfma_kernel,  dim3(H_, B_),    dim3(128), 0, stream,
                       u, AB, CB, (const unsigned*)WPh, Dp, FKf, y);
    hipLaunchKernelGGL(gemm_kernel,       dim3(16, 8, 8),  dim3(256), 0, stream,
                       Wb, y, bias, out);
}